// Round 1
// baseline (1301.129 us; speedup 1.0000x reference)
//
#include <hip/hip_runtime.h>

typedef unsigned int u32;
typedef unsigned short u16;

// ---------------- problem constants ----------------
#define NB   2048
#define NV   15
#define NT   16
#define NH   64
#define NTH  1024          // NT*NH
#define NLH  40
#define EPER 40
#define NN   (NB*NV)       // 30720
#define NE   (NB*EPER)     // 81920

// ---------------- ws layout (float-element offsets unless noted) ----------------
// converted inputs laid out in cumulative input order starting at 0
#define F_DATA 0
#define F_EA   983040
#define P_W1   1064960
#define P_B1   1065088
#define P_WG1  1065152
#define P_BG1  1069248
#define P_G1   1069312
#define P_BE1  1069376
#define P_WG2  1069440
#define P_BG2  1073536
#define P_G2   1073600
#define P_BE2  1073664
#define P_WF   1073728
#define P_BF   1135168
#define P_WIHF 1135232
#define P_WHHF 1145472
#define P_BIHF 1151872
#define P_BHHF 1152032
#define P_WIHB 1152192
#define P_WHHB 1162432
#define P_BIHB 1168832
#define P_BHHB 1168992
#define P_WC1  1169152
#define P_BC1  1170432
#define P_WC2  1170448
#define P_BC2  1170464
#define CVT_TOTAL 1170465
#define WFT_OFF   1170496   // Wf transposed [960][64]
#define STATS_OFF 1231936   // S1a,S2a,S1b,S2b,SC1,SH1,SC2,SH2 (8*1024)
#define XS_OFF    1240128   // Xs [16][2048][64] f32
#define FLAG_OFF  3337280   // int flag (1 = inputs are bf16)
#define BUFX_BYTE 13349376  // bf16 [NN][1024]  (x, later x1)
#define BUFY_BYTE 76263936  // bf16 [NN][1024]  (y1, later y2)

#define GCN_LDS_BYTES  148064
#define FC1_LDS_BYTES  86016
#define LSTM_LDS_BYTES 120992

__device__ const int d_cum[27] = {
  0, 983040, 1064960, 1065088, 1065152, 1069248, 1069312, 1069376,
  1069440, 1073536, 1073600, 1073664, 1073728, 1135168, 1135232, 1145472,
  1151872, 1152032, 1152192, 1162432, 1168832, 1168992, 1169152, 1170432,
  1170448, 1170464, 1170465};

struct Ptrs { const void* p[26]; };

__device__ inline float b2f(u16 u) { return __uint_as_float(((u32)u) << 16); }
__device__ inline u16 f2b(float f) {
  u32 u = __float_as_uint(f);
  u32 r = (u + 0x7FFFu + ((u >> 16) & 1u)) >> 16;
  return (u16)r;
}
__device__ inline float sigf(float x) { return 1.0f / (1.0f + __expf(-x)); }

// ---------------- dtype detector: bf16 inputs vs f32 inputs ----------------
__global__ void k_detect(const u16* __restrict__ raw, int* __restrict__ flag) {
  __shared__ int bad;
  if (threadIdx.x == 0) bad = 0;
  __syncthreads();
  for (int i = threadIdx.x; i < 4096; i += 256) {
    float f = b2f(raw[i]);
    if (!(fabsf(f) < 1000.0f)) atomicOr(&bad, 1);  // NaN/inf/huge -> f32 low-halves
  }
  __syncthreads();
  if (threadIdx.x == 0) *flag = bad ? 0 : 1;
}

// ---------------- convert all float inputs to f32 staging ----------------
__global__ void k_convert(Ptrs ptrs, float* __restrict__ W) {
  int gid = blockIdx.x * 256 + threadIdx.x;
  if (gid >= CVT_TOTAL) return;
  int flag = *(const int*)(W + FLAG_OFF);
  int ti = 0;
  #pragma unroll
  for (int i = 1; i < 26; ++i) ti += (gid >= d_cum[i]);
  int j = gid - d_cum[ti];
  const void* src = ptrs.p[ti];
  W[gid] = flag ? b2f(((const u16*)src)[j]) : ((const float*)src)[j];
}

// ---------------- conv1: x[n,t,h] = data[n,0,t]*W1[h,0]+data[n,1,t]*W1[h,1]+b1[h] ----------------
__global__ void k_conv1(const float* __restrict__ W, u16* __restrict__ bufX) {
  int gid = blockIdx.x * 256 + threadIdx.x;     // (n,t,h8)
  int h8 = gid & 7, t = (gid >> 3) & 15, n = gid >> 7;
  float d0 = W[F_DATA + n * 32 + t];
  float d1 = W[F_DATA + n * 32 + 16 + t];
  u32 out[4];
  #pragma unroll
  for (int jp = 0; jp < 4; ++jp) {
    int h = h8 * 8 + jp * 2;
    float v0 = fmaf(d0, W[P_W1 + h * 2],       fmaf(d1, W[P_W1 + h * 2 + 1],       W[P_B1 + h]));
    float v1 = fmaf(d0, W[P_W1 + (h + 1) * 2], fmaf(d1, W[P_W1 + (h + 1) * 2 + 1], W[P_B1 + h + 1]));
    out[jp] = (u32)f2b(v0) | ((u32)f2b(v1) << 16);
  }
  *reinterpret_cast<uint4*>(bufX + (size_t)gid * 8) = make_uint4(out[0], out[1], out[2], out[3]);
}

// ---------------- fused GCN layer (one block = one graph) ----------------
// LAYER==1: in = x(bufX)            -> y1 = relu(gcn1(x)) to bufY, stats
// LAYER==2: in = y1(bufY), res = x(bufX); x1 = bn1(y1)+x written back to bufX;
//           y2 = relu(gcn2(x1)) to bufY (same rows), stats
template<int LAYER>
__global__ __launch_bounds__(256, 1)
void k_gcn(const float* __restrict__ W, const int* __restrict__ ei,
           const u16* __restrict__ bufIn, u16* __restrict__ bufRes,
           u16* __restrict__ bufOut, float* __restrict__ S1, float* __restrict__ S2,
           int wgoff, int bgoff, int scoff, int shoff) {
  extern __shared__ float smem[];
  float* s_w    = smem;                 // 4096
  float* s_x    = smem + 4096;          // 15360
  float* s_a    = s_x + 15360;          // 15360
  float* s_sc   = s_a + 15360;          // 1024
  float* s_sh   = s_sc + 1024;          // 1024
  float* s_norm = s_sh + 1024;          // 40
  float* s_selfn= s_norm + 40;          // 16
  float* s_deg  = s_selfn + 16;         // 16
  int*   s_row  = (int*)(s_deg + 16);   // 40
  int*   s_col  = s_row + 40;           // 40

  int g = blockIdx.x, tid = threadIdx.x;
  #pragma unroll 4
  for (int i = tid; i < 4096; i += 256) s_w[i] = W[wgoff + i];
  if (LAYER == 2) {
    for (int i = tid; i < 1024; i += 256) { s_sc[i] = W[scoff + i]; s_sh[i] = W[shoff + i]; }
  }
  if (tid < 40) {
    s_row[tid] = ei[g * 40 + tid] - g * 15;
    s_col[tid] = ei[NE + g * 40 + tid] - g * 15;
  }
  if (tid >= 64 && tid < 80) s_deg[tid - 64] = 1.0f;   // self-loop weight
  __syncthreads();
  if (tid < 40) atomicAdd(&s_deg[s_col[tid]], W[F_EA + g * 40 + tid]);
  __syncthreads();
  if (tid < 15) { float dv = rsqrtf(s_deg[tid]); s_deg[tid] = dv; s_selfn[tid] = dv * dv; }
  __syncthreads();
  if (tid < 40) s_norm[tid] = s_deg[s_row[tid]] * W[F_EA + g * 40 + tid] * s_deg[s_col[tid]];

  // tile load (+BN1+residual for layer 2, and write x1 back)
  const u32* pin = (const u32*)(bufIn + g * 15360);
  if (LAYER == 1) {
    for (int i = tid; i < 7680; i += 256) {
      u32 u = pin[i];
      float2 v = make_float2(b2f((u16)(u & 0xffff)), b2f((u16)(u >> 16)));
      *reinterpret_cast<float2*>(s_x + 2 * i) = v;
    }
  } else {
    u32* pres = (u32*)(bufRes + g * 15360);
    for (int i = tid; i < 7680; i += 256) {
      u32 u = pin[i], ur = pres[i];
      int th = (2 * i) & 1023;
      float a = fmaf(b2f((u16)(u & 0xffff)), s_sc[th],     s_sh[th])     + b2f((u16)(ur & 0xffff));
      float b = fmaf(b2f((u16)(u >> 16)),    s_sc[th + 1], s_sh[th + 1]) + b2f((u16)(ur >> 16));
      *reinterpret_cast<float2*>(s_x + 2 * i) = make_float2(a, b);
      pres[i] = (u32)f2b(a) | ((u32)f2b(b) << 16);   // x1 out
    }
  }
  __syncthreads();

  // aggregation: s_a[j] = selfn[j]*s_x[j] + sum_e norm_e * s_x[row_e]  (per column)
  #pragma unroll
  for (int c4 = 0; c4 < 4; ++c4) {
    int tk = tid + c4 * 256;
    #pragma unroll
    for (int v = 0; v < 15; ++v) s_a[v * 1024 + tk] = s_selfn[v] * s_x[v * 1024 + tk];
    for (int e = 0; e < 40; ++e) {
      s_a[s_col[e] * 1024 + tk] += s_norm[e] * s_x[s_row[e] * 1024 + tk];
    }
  }
  __syncthreads();

  // GEMM: y[v,t,k] = relu( sum_h s_a[v,t,h] * Wg[h,k] + bg[k] );  2k x 2t per thread
  int k2 = tid & 31;
  int t0 = tid >> 5;                      // 0..7 ; t in {t0, t0+8}
  float bias0 = W[bgoff + k2], bias1 = W[bgoff + k2 + 32];
  float s1a[2][2] = {{0,0},{0,0}}, s2a[2][2] = {{0,0},{0,0}};
  const int rowbase = g * 15360;
  for (int v0 = 0; v0 < 15; v0 += 3) {
    float acc[2][2][3] = {};
    #pragma unroll 4
    for (int h = 0; h < 64; ++h) {
      float w0 = s_w[h * 64 + k2];
      float w1 = s_w[h * 64 + k2 + 32];
      #pragma unroll
      for (int vv = 0; vv < 3; ++vv) {
        float xa = s_a[(v0 + vv) * 1024 + t0 * 64 + h];
        float xb = s_a[(v0 + vv) * 1024 + (t0 + 8) * 64 + h];
        acc[0][0][vv] = fmaf(w0, xa, acc[0][0][vv]);
        acc[0][1][vv] = fmaf(w0, xb, acc[0][1][vv]);
        acc[1][0][vv] = fmaf(w1, xa, acc[1][0][vv]);
        acc[1][1][vv] = fmaf(w1, xb, acc[1][1][vv]);
      }
    }
    #pragma unroll
    for (int vv = 0; vv < 3; ++vv) {
      int v = v0 + vv;
      #pragma unroll
      for (int kb = 0; kb < 2; ++kb) {
        #pragma unroll
        for (int tb = 0; tb < 2; ++tb) {
          float y = acc[kb][tb][vv] + (kb ? bias1 : bias0);
          y = fmaxf(y, 0.0f);
          int t = t0 + tb * 8, k = k2 + kb * 32;
          bufOut[rowbase + v * 1024 + t * 64 + k] = f2b(y);
          s1a[kb][tb] += y;
          s2a[kb][tb] += y * y;
        }
      }
    }
  }
  #pragma unroll
  for (int kb = 0; kb < 2; ++kb)
    #pragma unroll
    for (int tb = 0; tb < 2; ++tb) {
      int idx = (t0 + tb * 8) * 64 + k2 + kb * 32;
      atomicAdd(&S1[idx], s1a[kb][tb]);
      atomicAdd(&S2[idx], s2a[kb][tb]);
    }
}

// ---------------- finalize BN stats -> fused scale/shift ----------------
__global__ void k_finalize(float* __restrict__ W, int layer) {
  int i = blockIdx.x * 256 + threadIdx.x;
  if (i >= 1024) return;
  int base = STATS_OFF + (layer == 1 ? 0 : 2048);
  int scb  = STATS_OFF + (layer == 1 ? 4096 : 6144);
  float m   = W[base + i] * (1.0f / 30720.0f);
  float var = W[base + 1024 + i] * (1.0f / 30720.0f) - m * m;
  float istd = rsqrtf(var + 1e-5f);
  int h = i & 63;
  float gm = W[(layer == 1 ? P_G1 : P_G2) + h];
  float bt = W[(layer == 1 ? P_BE1 : P_BE2) + h];
  float sc = gm * istd;
  W[scb + i] = sc;
  W[scb + 1024 + i] = bt - m * sc;
}

// ---------------- transpose Wf [64][960] -> WfT [960][64] ----------------
__global__ void k_twf(float* __restrict__ W) {
  int i = blockIdx.x * 256 + threadIdx.x;
  if (i >= 61440) return;
  int m = i >> 6, k = i & 63;
  W[WFT_OFF + i] = W[P_WF + k * 960 + m];
}

// ---------------- fc1: Xs[t,b,k] = relu( sum_{v,h} x2[b*15+v,t,h]*Wf[k,v*64+h] + bf[k] ) ----------------
__global__ __launch_bounds__(256, 1)
void k_fc1(const float* __restrict__ W, const u16* __restrict__ bufY2,
           const u16* __restrict__ bufX1, float* __restrict__ Xs) {
  extern __shared__ float smem[];
  float* s_x  = smem;            // 15360
  float* s_wf = smem + 15360;    // 4096
  float* s_sc = s_wf + 4096;     // 1024
  float* s_sh = s_sc + 1024;     // 1024
  int g = blockIdx.x, tid = threadIdx.x;
  for (int i = tid; i < 1024; i += 256) { s_sc[i] = W[STATS_OFF + 6144 + i]; s_sh[i] = W[STATS_OFF + 7168 + i]; }
  __syncthreads();
  const u32* py = (const u32*)(bufY2 + g * 15360);
  const u32* px = (const u32*)(bufX1 + g * 15360);
  for (int i = tid; i < 7680; i += 256) {
    u32 uy = py[i], ux = px[i];
    int th = (2 * i) & 1023;
    float a = fmaf(b2f((u16)(uy & 0xffff)), s_sc[th],     s_sh[th])     + b2f((u16)(ux & 0xffff));
    float b = fmaf(b2f((u16)(uy >> 16)),    s_sc[th + 1], s_sh[th + 1]) + b2f((u16)(ux >> 16));
    *reinterpret_cast<float2*>(s_x + 2 * i) = make_float2(a, b);
  }
  int k = tid & 63, t4 = tid >> 6;   // t in {t4, t4+4, t4+8, t4+12}
  float acc[4] = {0, 0, 0, 0};
  for (int v = 0; v < 15; ++v) {
    __syncthreads();
    for (int i = tid; i < 4096; i += 256) s_wf[i] = W[WFT_OFF + v * 4096 + i];
    __syncthreads();
    #pragma unroll 4
    for (int h = 0; h < 64; ++h) {
      float w = s_wf[h * 64 + k];
      #pragma unroll
      for (int tt = 0; tt < 4; ++tt)
        acc[tt] = fmaf(w, s_x[v * 1024 + (t4 + tt * 4) * 64 + h], acc[tt]);
    }
  }
  float bf = W[P_BF + k];
  #pragma unroll
  for (int tt = 0; tt < 4; ++tt) {
    int t = t4 + tt * 4;
    Xs[t * 131072 + g * 64 + k] = fmaxf(acc[tt] + bf, 0.0f);
  }
}

// ---------------- LSTM fwd (16 steps) + bwd (1 step) + classifier head ----------------
__global__ __launch_bounds__(256, 1)
void k_lstm(const float* __restrict__ W, const float* __restrict__ Xs,
            void* __restrict__ dout, const int* __restrict__ flagp) {
  extern __shared__ float smem[];
  float* s_wih  = smem;                  // 64*161
  float* s_whh  = s_wih + 10304;         // 40*161
  float* s_wihb = s_whh + 6440;          // 64*161
  float* s_bf   = s_wihb + 10304;        // 160
  float* s_bb   = s_bf + 160;            // 160
  float* s_h    = s_bb + 160;            // 320
  float* s_c    = s_h + 320;             // 320
  float* s_hb   = s_c + 320;             // 320
  float* s_g    = s_hb + 320;            // 1280
  float* s_xt   = s_g + 1280;            // 512
  float* s_cls  = s_xt + 512;            // 128

  int tid = threadIdx.x, r0 = blockIdx.x * 8;
  for (int i = tid; i < 160 * 64; i += 256) {
    int j = i >> 6, kk = i & 63;
    s_wih[kk * 161 + j]  = W[P_WIHF + i];
    s_wihb[kk * 161 + j] = W[P_WIHB + i];
  }
  for (int i = tid; i < 160 * 40; i += 256) {
    int j = i / 40, kk = i % 40;
    s_whh[kk * 161 + j] = W[P_WHHF + i];
  }
  for (int i = tid; i < 160; i += 256) {
    s_bf[i] = W[P_BIHF + i] + W[P_BHHF + i];
    s_bb[i] = W[P_BIHB + i] + W[P_BHHB + i];
  }
  for (int i = tid; i < 320; i += 256) { s_h[i] = 0.f; s_c[i] = 0.f; }
  __syncthreads();

  int r = tid >> 5, jb = tid & 31;
  for (int t = 0; t < 16; ++t) {
    for (int i = tid; i < 512; i += 256)
      s_xt[i] = Xs[t * 131072 + (r0 + (i >> 6)) * 64 + (i & 63)];
    __syncthreads();
    float acc[5];
    #pragma unroll
    for (int q = 0; q < 5; ++q) acc[q] = s_bf[jb + 32 * q];
    #pragma unroll 2
    for (int kk = 0; kk < 64; ++kk) {
      float xv = s_xt[r * 64 + kk];
      #pragma unroll
      for (int q = 0; q < 5; ++q) acc[q] = fmaf(xv, s_wih[kk * 161 + jb + 32 * q], acc[q]);
    }
    #pragma unroll 2
    for (int kk = 0; kk < 40; ++kk) {
      float hv = s_h[r * 40 + kk];
      #pragma unroll
      for (int q = 0; q < 5; ++q) acc[q] = fmaf(hv, s_whh[kk * 161 + jb + 32 * q], acc[q]);
    }
    #pragma unroll
    for (int q = 0; q < 5; ++q) s_g[r * 160 + jb + 32 * q] = acc[q];
    __syncthreads();
    for (int idx = tid; idx < 320; idx += 256) {
      int rr = idx / 40, jj = idx % 40;
      float ig = s_g[rr * 160 + jj],      fg = s_g[rr * 160 + 40 + jj];
      float gg = s_g[rr * 160 + 80 + jj], og = s_g[rr * 160 + 120 + jj];
      float c = sigf(fg) * s_c[idx] + sigf(ig) * tanhf(gg);
      s_c[idx] = c;
      s_h[idx] = sigf(og) * tanhf(c);
    }
    __syncthreads();
  }
  // backward LSTM: only hs_b[0] is used = one step on Xs[15] from zero state (s_xt holds t=15)
  {
    float acc[5];
    #pragma unroll
    for (int q = 0; q < 5; ++q) acc[q] = s_bb[jb + 32 * q];
    #pragma unroll 2
    for (int kk = 0; kk < 64; ++kk) {
      float xv = s_xt[r * 64 + kk];
      #pragma unroll
      for (int q = 0; q < 5; ++q) acc[q] = fmaf(xv, s_wihb[kk * 161 + jb + 32 * q], acc[q]);
    }
    #pragma unroll
    for (int q = 0; q < 5; ++q) s_g[r * 160 + jb + 32 * q] = acc[q];
    __syncthreads();
    for (int idx = tid; idx < 320; idx += 256) {
      int rr = idx / 40, jj = idx % 40;
      float ig = s_g[rr * 160 + jj], gg = s_g[rr * 160 + 80 + jj], og = s_g[rr * 160 + 120 + jj];
      float c = sigf(ig) * tanhf(gg);
      s_hb[idx] = sigf(og) * tanhf(c);
    }
    __syncthreads();
  }
  // classifier: relu([h_f|h_b] @ Wc1^T + bc1) @ Wc2^T + bc2
  if (tid < 128) {
    int rr = tid >> 4, jj = tid & 15;
    float a = W[P_BC1 + jj];
    for (int p = 0; p < 40; ++p) a = fmaf(W[P_WC1 + jj * 80 + p],      s_h[rr * 40 + p],  a);
    for (int p = 0; p < 40; ++p) a = fmaf(W[P_WC1 + jj * 80 + 40 + p], s_hb[rr * 40 + p], a);
    s_cls[rr * 16 + jj] = fmaxf(a, 0.0f);
  }
  __syncthreads();
  if (tid < 8) {
    float o = W[P_BC2];
    #pragma unroll
    for (int jj = 0; jj < 16; ++jj) o = fmaf(W[P_WC2 + jj], s_cls[tid * 16 + jj], o);
    if (*flagp) ((u16*)dout)[r0 + tid] = f2b(o);
    else        ((float*)dout)[r0 + tid] = o;
  }
}

// ---------------- launch ----------------
extern "C" void kernel_launch(void* const* d_in, const int* in_sizes, int n_in,
                              void* d_out, int out_size, void* d_ws, size_t ws_size,
                              hipStream_t stream) {
  float* W = (float*)d_ws;
  u16* bufX = (u16*)((char*)d_ws + BUFX_BYTE);
  u16* bufY = (u16*)((char*)d_ws + BUFY_BYTE);
  const int* ei = (const int*)d_in[26];

  (void)hipFuncSetAttribute(reinterpret_cast<const void*>(&k_gcn<1>),
                            hipFuncAttributeMaxDynamicSharedMemorySize, GCN_LDS_BYTES);
  (void)hipFuncSetAttribute(reinterpret_cast<const void*>(&k_gcn<2>),
                            hipFuncAttributeMaxDynamicSharedMemorySize, GCN_LDS_BYTES);
  (void)hipFuncSetAttribute(reinterpret_cast<const void*>(&k_fc1),
                            hipFuncAttributeMaxDynamicSharedMemorySize, FC1_LDS_BYTES);
  (void)hipFuncSetAttribute(reinterpret_cast<const void*>(&k_lstm),
                            hipFuncAttributeMaxDynamicSharedMemorySize, LSTM_LDS_BYTES);

  hipMemsetAsync(W + STATS_OFF, 0, 4096 * sizeof(float), stream);  // S1a,S2a,S1b,S2b
  k_detect<<<1, 256, 0, stream>>>((const u16*)d_in[0], (int*)(W + FLAG_OFF));
  Ptrs ptrs;
  for (int i = 0; i < 26; ++i) ptrs.p[i] = d_in[i];
  k_convert<<<(CVT_TOTAL + 255) / 256, 256, 0, stream>>>(ptrs, W);
  k_conv1<<<NN * 16 * 8 / 256, 256, 0, stream>>>(W, bufX);
  k_gcn<1><<<NB, 256, GCN_LDS_BYTES, stream>>>(W, ei, bufX, nullptr, bufY,
      W + STATS_OFF, W + STATS_OFF + 1024, P_WG1, P_BG1, 0, 0);
  k_finalize<<<4, 256, 0, stream>>>(W, 1);
  k_gcn<2><<<NB, 256, GCN_LDS_BYTES, stream>>>(W, ei, bufY, bufX, bufY,
      W + STATS_OFF + 2048, W + STATS_OFF + 3072, P_WG2, P_BG2,
      STATS_OFF + 4096, STATS_OFF + 5120);
  k_finalize<<<4, 256, 0, stream>>>(W, 2);
  k_twf<<<240, 256, 0, stream>>>(W);
  k_fc1<<<NB, 256, FC1_LDS_BYTES, stream>>>(W, bufY, bufX, W + XS_OFF);
  k_lstm<<<256, 256, LSTM_LDS_BYTES, stream>>>(W, W + XS_OFF, d_out, (const int*)(W + FLAG_OFF));
}

// Round 4
// 411.380 us; speedup vs baseline: 3.1628x; 3.1628x over previous
//
#include <hip/hip_runtime.h>

typedef unsigned int u32;
typedef unsigned short u16;
typedef __attribute__((ext_vector_type(8))) short bf16x8;
typedef __attribute__((ext_vector_type(4))) float f32x4;

// ---------------- problem constants ----------------
#define NB   2048
#define NV   15
#define NT   16
#define NH   64
#define NLH  40
#define EPER 40
#define NN   (NB*NV)       // 30720
#define NE   (NB*EPER)     // 81920

// ---------------- ws layout (float-element offsets unless noted) ----------------
#define F_DATA 0
#define F_EA   983040
#define P_W1   1064960
#define P_B1   1065088
#define P_WG1  1065152
#define P_BG1  1069248
#define P_G1   1069312
#define P_BE1  1069376
#define P_WG2  1069440
#define P_BG2  1073536
#define P_G2   1073600
#define P_BE2  1073664
#define P_WF   1073728
#define P_BF   1135168
#define P_WIHF 1135232
#define P_WHHF 1145472
#define P_BIHF 1151872
#define P_BHHF 1152032
#define P_WIHB 1152192
#define P_WHHB 1162432
#define P_BIHB 1168832
#define P_BHHB 1168992
#define P_WC1  1169152
#define P_BC1  1170432
#define P_WC2  1170448
#define P_BC2  1170464
#define CVT_TOTAL 1170465
#define WFB_OFF   1170496   // u16 frags: WfB[61440] ++ WgB1[4096] ++ WgB2[4096]
#define STATS_OFF 1231936   // S1a,S2a,S1b,S2b,SC1,SH1,SC2,SH2 (8*1024)
#define XS_OFF    1240128   // Xs [16][2048][64] f32
#define FLAG_OFF  3337280   // int flag (1 = inputs are bf16)
#define BUFX_BYTE 13349376  // bf16 [NN][1024]  (x, later x1)
#define BUFY_BYTE 76263936  // bf16 [NN][1024]  (y1, later y2)

#define LSTM_LDS_BYTES 120992

__device__ const int d_cum[27] = {
  0, 983040, 1064960, 1065088, 1065152, 1069248, 1069312, 1069376,
  1069440, 1073536, 1073600, 1073664, 1073728, 1135168, 1135232, 1145472,
  1151872, 1152032, 1152192, 1162432, 1168832, 1168992, 1169152, 1170432,
  1170448, 1170464, 1170465};

struct Ptrs { const void* p[26]; };

__device__ inline float b2f(u16 u) { return __uint_as_float(((u32)u) << 16); }
__device__ inline u16 f2b(float f) {
  u32 u = __float_as_uint(f);
  u32 r = (u + 0x7FFFu + ((u >> 16) & 1u)) >> 16;
  return (u16)r;
}
__device__ inline float sigf(float x) { return 1.0f / (1.0f + __expf(-x)); }

// ---------------- dtype detector: bf16 inputs vs f32 inputs ----------------
__global__ void k_detect(const u16* __restrict__ raw, int* __restrict__ flag) {
  __shared__ int bad;
  if (threadIdx.x == 0) bad = 0;
  __syncthreads();
  for (int i = threadIdx.x; i < 4096; i += 256) {
    float f = b2f(raw[i]);
    if (!(fabsf(f) < 1000.0f)) atomicOr(&bad, 1);  // NaN/inf/huge -> f32 low-halves
  }
  __syncthreads();
  if (threadIdx.x == 0) *flag = bad ? 0 : 1;
}

// ---------------- convert all float inputs to f32 staging ----------------
__global__ void k_convert(Ptrs ptrs, float* __restrict__ W) {
  int gid = blockIdx.x * 256 + threadIdx.x;
  if (gid >= CVT_TOTAL) return;
  int flag = *(const int*)(W + FLAG_OFF);
  int ti = 0;
  #pragma unroll
  for (int i = 1; i < 26; ++i) ti += (gid >= d_cum[i]);
  int j = gid - d_cum[ti];
  const void* src = ptrs.p[ti];
  W[gid] = flag ? b2f(((const u16*)src)[j]) : ((const float*)src)[j];
}

// ---------------- conv1 ----------------
__global__ void k_conv1(const float* __restrict__ W, u16* __restrict__ bufX) {
  int gid = blockIdx.x * 256 + threadIdx.x;     // (n,t,h8)
  int h8 = gid & 7, t = (gid >> 3) & 15, n = gid >> 7;
  float d0 = W[F_DATA + n * 32 + t];
  float d1 = W[F_DATA + n * 32 + 16 + t];
  u32 out[4];
  #pragma unroll
  for (int jp = 0; jp < 4; ++jp) {
    int h = h8 * 8 + jp * 2;
    float v0 = fmaf(d0, W[P_W1 + h * 2],       fmaf(d1, W[P_W1 + h * 2 + 1],       W[P_B1 + h]));
    float v1 = fmaf(d0, W[P_W1 + (h + 1) * 2], fmaf(d1, W[P_W1 + (h + 1) * 2 + 1], W[P_B1 + h + 1]));
    out[jp] = (u32)f2b(v0) | ((u32)f2b(v1) << 16);
  }
  *reinterpret_cast<uint4*>(bufX + (size_t)gid * 8) = make_uint4(out[0], out[1], out[2], out[3]);
}

// ---------------- pre-swizzle MFMA B-fragments: Wf, Wg1, Wg2 ----------------
// Wf frag:  i=((ks*4+kt)*64+lane)*8+j -> Wf[kout=kt*16+(lane&15)][m=ks*32+(lane>>4)*8+j]
// Wg frag:  r=((ks*4+nt)*64+lane)*8+j -> Wg[h=ks*32+(lane>>4)*8+j][k=nt*16+(lane&15)]
__global__ void k_preswz(const float* __restrict__ W, u16* __restrict__ WfB) {
  int i = blockIdx.x * 256 + threadIdx.x;
  if (i < 61440) {
    int j = i & 7, lane = (i >> 3) & 63, kt = (i >> 9) & 3, ks = i >> 11;
    int kout = kt * 16 + (lane & 15);
    int m = ks * 32 + ((lane >> 4) << 3) + j;
    WfB[i] = f2b(W[P_WF + kout * 960 + m]);
  } else if (i < 69632) {
    int ii = i - 61440;
    int L = ii >> 12, r = ii & 4095;
    int j = r & 7, lane = (r >> 3) & 63, nt = (r >> 9) & 3, ks = (r >> 11) & 1;
    int h = ks * 32 + ((lane >> 4) << 3) + j;
    int k = nt * 16 + (lane & 15);
    WfB[i] = f2b(W[(L ? P_WG2 : P_WG1) + h * 64 + k]);
  }
}

// ---------------- fused GCN layer (one block = one graph, 4 waves, MFMA) ----
// LAYER==1: in = x(bufX)            -> y1 = relu(gcn1(x)) to bufY, stats
// LAYER==2: in = y1(bufY), res = x(bufX); x1 = bn1(y1)+x back to bufX;
//           y2 = relu(gcn2(x1)) to bufY, stats
// Aggregation via dense normalized-adjacency M (15x15), in-place per column.
template<int LAYER>
__global__ __launch_bounds__(256, 4)
void k_gcn(const float* __restrict__ W, const int* __restrict__ ei,
           const u16* __restrict__ bufIn, u16* __restrict__ bufRes,
           u16* __restrict__ bufOut, const u16* __restrict__ WgB,
           float* __restrict__ S1, float* __restrict__ S2,
           int bgoff, int scoff, int shoff) {
  __shared__ u16 s_x[15360];     // 30720 B, swizzled [v][t][h] bf16 (byte ^= (t&7)<<4)
  __shared__ float s_m[240];     // M[vc][vr] padded rows of 16
  __shared__ float s_deg[16];
  __shared__ int s_row[40], s_col[40];

  int g = blockIdx.x, tid = threadIdx.x;
  // phase A: edges, deg init, zero M, stage tile into swizzled LDS
  float ew = 0.f; int er = 0, ec = 0;
  if (tid < 40) {
    er = ei[g * 40 + tid] - g * 15;
    ec = ei[NE + g * 40 + tid] - g * 15;
    ew = W[F_EA + g * 40 + tid];
    s_row[tid] = er; s_col[tid] = ec;
  }
  if (tid >= 64 && tid < 80) s_deg[tid - 64] = 1.0f;   // self-loop weight
  for (int i = tid; i < 240; i += 256) s_m[i] = 0.f;

  const u32* pin = (const u32*)(bufIn + g * 15360);
  u32* sx32 = (u32*)s_x;
  if (LAYER == 1) {
    #pragma unroll
    for (int c = 0; c < 30; ++c) {
      int i = tid + c * 256;
      int t = (i >> 5) & 15;
      sx32[(((u32)(i << 2)) ^ (((u32)(t & 7)) << 4)) >> 2] = pin[i];
    }
  } else {
    u32* pres = (u32*)(bufRes + g * 15360);
    #pragma unroll 2
    for (int c = 0; c < 30; ++c) {
      int i = tid + c * 256;
      u32 uy = pin[i], ux = pres[i];
      int th = (2 * i) & 1023;
      int t = th >> 6;
      float a = fmaf(b2f((u16)(uy & 0xffff)), W[scoff + th],     W[shoff + th])     + b2f((u16)(ux & 0xffff));
      float b = fmaf(b2f((u16)(uy >> 16)),    W[scoff + th + 1], W[shoff + th + 1]) + b2f((u16)(ux >> 16));
      u32 pk = (u32)f2b(a) | ((u32)f2b(b) << 16);
      pres[i] = pk;                                        // x1 back to global
      sx32[(((u32)(i << 2)) ^ (((u32)(t & 7)) << 4)) >> 2] = pk;
    }
  }
  __syncthreads();
  // phase B: weighted in-degree
  if (tid < 40) atomicAdd(&s_deg[ec], ew);
  __syncthreads();
  // phase C: deg -> dinv
  if (tid < 15) s_deg[tid] = rsqrtf(s_deg[tid]);
  __syncthreads();
  // phase D: build M: M[col][row] += dinv[row]*ew*dinv[col]; diag += dinv^2
  if (tid < 40) atomicAdd(&s_m[ec * 16 + er], s_deg[er] * ew * s_deg[ec]);
  if (tid >= 64 && tid < 80) {
    float dv = s_deg[tid - 64];
    atomicAdd(&s_m[(tid - 64) * 17], dv * dv);
  }
  __syncthreads();

  // aggregation, in place: each thread owns 4 columns (2 u32 pairs)
  {
    float x0[15], x1[15], x2[15], x3[15];
    int p0 = tid, p1 = tid + 256;
    int t0 = p0 >> 5, h0 = (2 * p0) & 63;
    int t1 = p1 >> 5, h1 = (2 * p1) & 63;
    u32 ba0 = ((u32)(t0 * 128 + h0 * 2)) ^ (((u32)(t0 & 7)) << 4);
    u32 ba1 = ((u32)(t1 * 128 + h1 * 2)) ^ (((u32)(t1 & 7)) << 4);
    #pragma unroll
    for (int v = 0; v < 15; ++v) {
      u32 ua = sx32[(ba0 + v * 2048) >> 2];
      u32 ub = sx32[(ba1 + v * 2048) >> 2];
      x0[v] = b2f((u16)(ua & 0xffff)); x1[v] = b2f((u16)(ua >> 16));
      x2[v] = b2f((u16)(ub & 0xffff)); x3[v] = b2f((u16)(ub >> 16));
    }
    #pragma unroll
    for (int vc = 0; vc < 15; ++vc) {
      float a0 = 0.f, a1 = 0.f, a2 = 0.f, a3 = 0.f;
      #pragma unroll
      for (int vr = 0; vr < 15; ++vr) {
        float m = s_m[vc * 16 + vr];
        a0 = fmaf(m, x0[vr], a0); a1 = fmaf(m, x1[vr], a1);
        a2 = fmaf(m, x2[vr], a2); a3 = fmaf(m, x3[vr], a3);
      }
      sx32[(ba0 + vc * 2048) >> 2] = (u32)f2b(a0) | ((u32)f2b(a1) << 16);
      sx32[(ba1 + vc * 2048) >> 2] = (u32)f2b(a2) | ((u32)f2b(a3) << 16);
    }
  }
  __syncthreads();

  // MFMA GEMM: y[v,t,k] = relu(agg[v,t,:] . Wg[:,k] + bg[k]); wave = n-tile
  int wid = tid >> 6, lane = tid & 63;
  int tA = lane & 15, kg = lane >> 4;
  const bf16x8* wb = (const bf16x8*)WgB;
  bf16x8 bf0 = wb[(0 * 4 + wid) * 64 + lane];
  bf16x8 bf1 = wb[(1 * 4 + wid) * 64 + lane];
  int kout = wid * 16 + tA;
  float bias = W[bgoff + kout];
  f32x4 acc[15];
  #pragma unroll
  for (int v = 0; v < 15; ++v) acc[v] = (f32x4){0.f, 0.f, 0.f, 0.f};
  u32 sw = ((u32)(tA & 7)) << 4;
  #pragma unroll
  for (int v = 0; v < 15; ++v) {
    u32 bb = (u32)(v * 2048 + tA * 128 + kg * 16);
    bf16x8 a0 = *(const bf16x8*)(s_x + ((bb ^ sw) >> 1));
    bf16x8 a1 = *(const bf16x8*)(s_x + (((bb + 64) ^ sw) >> 1));
    acc[v] = __builtin_amdgcn_mfma_f32_16x16x32_bf16(a0, bf0, acc[v], 0, 0, 0);
    acc[v] = __builtin_amdgcn_mfma_f32_16x16x32_bf16(a1, bf1, acc[v], 0, 0, 0);
  }
  float s1r[4] = {0.f, 0.f, 0.f, 0.f}, s2r[4] = {0.f, 0.f, 0.f, 0.f};
  u16* pout = bufOut + g * 15360;
  #pragma unroll
  for (int v = 0; v < 15; ++v) {
    #pragma unroll
    for (int r = 0; r < 4; ++r) {
      float y = fmaxf(acc[v][r] + bias, 0.f);
      pout[v * 1024 + (kg * 4 + r) * 64 + kout] = f2b(y);
      s1r[r] += y; s2r[r] += y * y;
    }
  }
  #pragma unroll
  for (int r = 0; r < 4; ++r) {
    int idx = (kg * 4 + r) * 64 + kout;
    atomicAdd(&S1[idx], s1r[r]);
    atomicAdd(&S2[idx], s2r[r]);
  }
}

// ---------------- finalize BN stats -> fused scale/shift ----------------
__global__ void k_finalize(float* __restrict__ W, int layer) {
  int i = blockIdx.x * 256 + threadIdx.x;
  if (i >= 1024) return;
  int base = STATS_OFF + (layer == 1 ? 0 : 2048);
  int scb  = STATS_OFF + (layer == 1 ? 4096 : 6144);
  float m   = W[base + i] * (1.0f / 30720.0f);
  float var = W[base + 1024 + i] * (1.0f / 30720.0f) - m * m;
  float istd = rsqrtf(var + 1e-5f);
  int h = i & 63;
  float gm = W[(layer == 1 ? P_G1 : P_G2) + h];
  float bt = W[(layer == 1 ? P_BE1 : P_BE2) + h];
  float sc = gm * istd;
  W[scb + i] = sc;
  W[scb + 1024 + i] = bt - m * sc;
}

// ---------------- fc1 via MFMA: Xs[t,b,k] = relu(x2[b] . Wf[k] + bf[k]) ----
__global__ __launch_bounds__(256, 4)
void k_fc1(const float* __restrict__ W, const u16* __restrict__ bufY2,
           const u16* __restrict__ bufX1, const u16* __restrict__ WfB,
           float* __restrict__ Xs) {
  __shared__ u16 s_x[15360];            // 30720 B, swizzled [v][t][h] bf16
  __shared__ float s_sc[1024], s_sh[1024];
  int g = blockIdx.x, tid = threadIdx.x;
  for (int i = tid; i < 1024; i += 256) {
    s_sc[i] = W[STATS_OFF + 6144 + i];
    s_sh[i] = W[STATS_OFF + 7168 + i];
  }
  __syncthreads();
  const u32* py = (const u32*)(bufY2 + g * 15360);
  const u32* px = (const u32*)(bufX1 + g * 15360);
  u32* sx32 = (u32*)s_x;
  for (int i = tid; i < 7680; i += 256) {
    u32 uy = py[i], ux = px[i];
    int e = 2 * i;
    int th = e & 1023;
    int t = th >> 6;
    float a = fmaf(b2f((u16)(uy & 0xffff)), s_sc[th],     s_sh[th])     + b2f((u16)(ux & 0xffff));
    float b = fmaf(b2f((u16)(uy >> 16)),    s_sc[th + 1], s_sh[th + 1]) + b2f((u16)(ux >> 16));
    u32 byte = ((u32)(e << 1)) ^ (((u32)(t & 7)) << 4);
    sx32[byte >> 2] = (u32)f2b(a) | ((u32)f2b(b) << 16);
  }
  __syncthreads();

  int wid = tid >> 6, lane = tid & 63;
  int tA = lane & 15, kg = lane >> 4;
  f32x4 acc = {0.f, 0.f, 0.f, 0.f};
  const bf16x8* wf = (const bf16x8*)WfB;
  #pragma unroll 2
  for (int ks = 0; ks < 30; ++ks) {
    int v = ks >> 1, half = ks & 1;
    u32 byte = (u32)(v * 2048 + tA * 128 + (half * 32 + kg * 8) * 2) ^ (((u32)(tA & 7)) << 4);
    bf16x8 afrag = *(const bf16x8*)(s_x + (byte >> 1));
    bf16x8 bfrag = wf[(ks * 4 + wid) * 64 + lane];
    acc = __builtin_amdgcn_mfma_f32_16x16x32_bf16(afrag, bfrag, acc, 0, 0, 0);
  }
  int kout = wid * 16 + (lane & 15);
  float bias = W[P_BF + kout];
  #pragma unroll
  for (int r = 0; r < 4; ++r) {
    int t = (lane >> 4) * 4 + r;
    Xs[t * 131072 + g * 64 + kout] = fmaxf(acc[r] + bias, 0.0f);
  }
}

// ---------------- LSTM fwd (16 steps) + bwd (1 step) + classifier head ----
__global__ __launch_bounds__(256, 1)
void k_lstm(const float* __restrict__ W, const float* __restrict__ Xs,
            void* __restrict__ dout, const int* __restrict__ flagp) {
  extern __shared__ float smem[];
  float* s_wih  = smem;                  // 64*161
  float* s_whh  = s_wih + 10304;         // 40*161
  float* s_wihb = s_whh + 6440;          // 64*161
  float* s_bf   = s_wihb + 10304;        // 160
  float* s_bb   = s_bf + 160;            // 160
  float* s_h    = s_bb + 160;            // 320
  float* s_c    = s_h + 320;             // 320
  float* s_hb   = s_c + 320;             // 320
  float* s_g    = s_hb + 320;            // 1280
  float* s_xt   = s_g + 1280;            // 512
  float* s_cls  = s_xt + 512;            // 128

  int tid = threadIdx.x, r0 = blockIdx.x * 8;
  for (int i = tid; i < 160 * 64; i += 256) {
    int j = i >> 6, kk = i & 63;
    s_wih[kk * 161 + j]  = W[P_WIHF + i];
    s_wihb[kk * 161 + j] = W[P_WIHB + i];
  }
  for (int i = tid; i < 160 * 40; i += 256) {
    int j = i / 40, kk = i % 40;
    s_whh[kk * 161 + j] = W[P_WHHF + i];
  }
  for (int i = tid; i < 160; i += 256) {
    s_bf[i] = W[P_BIHF + i] + W[P_BHHF + i];
    s_bb[i] = W[P_BIHB + i] + W[P_BHHB + i];
  }
  for (int i = tid; i < 320; i += 256) { s_h[i] = 0.f; s_c[i] = 0.f; }
  __syncthreads();

  int r = tid >> 5, jb = tid & 31;
  for (int t = 0; t < 16; ++t) {
    for (int i = tid; i < 512; i += 256)
      s_xt[i] = Xs[t * 131072 + (r0 + (i >> 6)) * 64 + (i & 63)];
    __syncthreads();
    float acc[5];
    #pragma unroll
    for (int q = 0; q < 5; ++q) acc[q] = s_bf[jb + 32 * q];
    #pragma unroll 2
    for (int kk = 0; kk < 64; ++kk) {
      float xv = s_xt[r * 64 + kk];
      #pragma unroll
      for (int q = 0; q < 5; ++q) acc[q] = fmaf(xv, s_wih[kk * 161 + jb + 32 * q], acc[q]);
    }
    #pragma unroll 2
    for (int kk = 0; kk < 40; ++kk) {
      float hv = s_h[r * 40 + kk];
      #pragma unroll
      for (int q = 0; q < 5; ++q) acc[q] = fmaf(hv, s_whh[kk * 161 + jb + 32 * q], acc[q]);
    }
    #pragma unroll
    for (int q = 0; q < 5; ++q) s_g[r * 160 + jb + 32 * q] = acc[q];
    __syncthreads();
    for (int idx = tid; idx < 320; idx += 256) {
      int rr = idx / 40, jj = idx % 40;
      float ig = s_g[rr * 160 + jj],      fg = s_g[rr * 160 + 40 + jj];
      float gg = s_g[rr * 160 + 80 + jj], og = s_g[rr * 160 + 120 + jj];
      float c = sigf(fg) * s_c[idx] + sigf(ig) * tanhf(gg);
      s_c[idx] = c;
      s_h[idx] = sigf(og) * tanhf(c);
    }
    __syncthreads();
  }
  // backward LSTM: only hs_b[0] used = one step on Xs[15] (s_xt holds t=15)
  {
    float acc[5];
    #pragma unroll
    for (int q = 0; q < 5; ++q) acc[q] = s_bb[jb + 32 * q];
    #pragma unroll 2
    for (int kk = 0; kk < 64; ++kk) {
      float xv = s_xt[r * 64 + kk];
      #pragma unroll
      for (int q = 0; q < 5; ++q) acc[q] = fmaf(xv, s_wihb[kk * 161 + jb + 32 * q], acc[q]);
    }
    #pragma unroll
    for (int q = 0; q < 5; ++q) s_g[r * 160 + jb + 32 * q] = acc[q];
    __syncthreads();
    for (int idx = tid; idx < 320; idx += 256) {
      int rr = idx / 40, jj = idx % 40;
      float ig = s_g[rr * 160 + jj], gg = s_g[rr * 160 + 80 + jj], og = s_g[rr * 160 + 120 + jj];
      float c = sigf(ig) * tanhf(gg);
      s_hb[idx] = sigf(og) * tanhf(c);
    }
    __syncthreads();
  }
  if (tid < 128) {
    int rr = tid >> 4, jj = tid & 15;
    float a = W[P_BC1 + jj];
    for (int p = 0; p < 40; ++p) a = fmaf(W[P_WC1 + jj * 80 + p],      s_h[rr * 40 + p],  a);
    for (int p = 0; p < 40; ++p) a = fmaf(W[P_WC1 + jj * 80 + 40 + p], s_hb[rr * 40 + p], a);
    s_cls[rr * 16 + jj] = fmaxf(a, 0.0f);
  }
  __syncthreads();
  if (tid < 8) {
    float o = W[P_BC2];
    #pragma unroll
    for (int jj = 0; jj < 16; ++jj) o = fmaf(W[P_WC2 + jj], s_cls[tid * 16 + jj], o);
    if (*flagp) ((u16*)dout)[r0 + tid] = f2b(o);
    else        ((float*)dout)[r0 + tid] = o;
  }
}

// ---------------- launch ----------------
extern "C" void kernel_launch(void* const* d_in, const int* in_sizes, int n_in,
                              void* d_out, int out_size, void* d_ws, size_t ws_size,
                              hipStream_t stream) {
  float* W = (float*)d_ws;
  u16* bufX = (u16*)((char*)d_ws + BUFX_BYTE);
  u16* bufY = (u16*)((char*)d_ws + BUFY_BYTE);
  u16* WfB  = (u16*)(W + WFB_OFF);
  const int* ei = (const int*)d_in[26];

  (void)hipFuncSetAttribute(reinterpret_cast<const void*>(&k_lstm),
                            hipFuncAttributeMaxDynamicSharedMemorySize, LSTM_LDS_BYTES);

  hipMemsetAsync(W + STATS_OFF, 0, 4096 * sizeof(float), stream);
  k_detect<<<1, 256, 0, stream>>>((const u16*)d_in[0], (int*)(W + FLAG_OFF));
  Ptrs ptrs;
  for (int i = 0; i < 26; ++i) ptrs.p[i] = d_in[i];
  k_convert<<<(CVT_TOTAL + 255) / 256, 256, 0, stream>>>(ptrs, W);
  k_preswz<<<272, 256, 0, stream>>>(W, WfB);
  k_conv1<<<NN * 16 * 8 / 256, 256, 0, stream>>>(W, bufX);
  k_gcn<1><<<NB, 256, 0, stream>>>(W, ei, bufX, nullptr, bufY, WfB + 61440,
      W + STATS_OFF, W + STATS_OFF + 1024, P_BG1, 0, 0);
  k_finalize<<<4, 256, 0, stream>>>(W, 1);
  k_gcn<2><<<NB, 256, 0, stream>>>(W, ei, bufY, bufX, bufY, WfB + 65536,
      W + STATS_OFF + 2048, W + STATS_OFF + 3072, P_BG2,
      STATS_OFF + 4096, STATS_OFF + 5120);
  k_finalize<<<4, 256, 0, stream>>>(W, 2);
  k_fc1<<<NB, 256, 0, stream>>>(W, bufY, bufX, WfB, W + XS_OFF);
  k_lstm<<<256, 256, LSTM_LDS_BYTES, stream>>>(W, W + XS_OFF, d_out, (const int*)(W + FLAG_OFF));
}

// Round 5
// 377.487 us; speedup vs baseline: 3.4468x; 1.0898x over previous
//
#include <hip/hip_runtime.h>

typedef unsigned int u32;
typedef unsigned short u16;
typedef __attribute__((ext_vector_type(8))) short bf16x8;
typedef __attribute__((ext_vector_type(4))) float f32x4;

// ---------------- problem constants ----------------
#define NB   2048
#define NV   15
#define NT   16
#define NH   64
#define NLH  40
#define EPER 40
#define NN   (NB*NV)       // 30720
#define NE   (NB*EPER)     // 81920

// ---------------- ws layout (float-element offsets unless noted) ----------------
#define F_DATA 0
#define F_EA   983040
#define P_W1   1064960
#define P_B1   1065088
#define P_WG1  1065152
#define P_BG1  1069248
#define P_G1   1069312
#define P_BE1  1069376
#define P_WG2  1069440
#define P_BG2  1073536
#define P_G2   1073600
#define P_BE2  1073664
#define P_WF   1073728
#define P_BF   1135168
#define P_WIHF 1135232
#define P_WHHF 1145472
#define P_BIHF 1151872
#define P_BHHF 1152032
#define P_WIHB 1152192
#define P_WHHB 1162432
#define P_BIHB 1168832
#define P_BHHB 1168992
#define P_WC1  1169152
#define P_BC1  1170432
#define P_WC2  1170448
#define P_BC2  1170464
#define CVT_TOTAL 1170465
#define WFB_OFF   1170496   // u16 frags: WfB[61440] ++ WgB1[4096] ++ WgB2[4096] (34816 f32 slots)
#define WIHT_OFF  1205504   // f32 WihT_f[64][160] ++ WihT_b[64][160] (20480 floats)
#define STATS_OFF 1231936   // S1a,S2a,S1b,S2b,SC1,SH1,SC2,SH2 (8*1024)
#define XS_OFF    1240128   // Xs [16][2048][64] f32
#define FLAG_OFF  3337280   // int flag (1 = inputs are bf16)
#define BUFX_BYTE 13349376  // bf16 [NN][1024]  (x, later x1); after fc1: gxf/gxb f32
#define BUFY_BYTE 76263936  // bf16 [NN][1024]  (y1, later y2)

__device__ const int d_cum[27] = {
  0, 983040, 1064960, 1065088, 1065152, 1069248, 1069312, 1069376,
  1069440, 1073536, 1073600, 1073664, 1073728, 1135168, 1135232, 1145472,
  1151872, 1152032, 1152192, 1162432, 1168832, 1168992, 1169152, 1170432,
  1170448, 1170464, 1170465};

struct Ptrs { const void* p[26]; };

__device__ inline float b2f(u16 u) { return __uint_as_float(((u32)u) << 16); }
__device__ inline u16 f2b(float f) {
  u32 u = __float_as_uint(f);
  u32 r = (u + 0x7FFFu + ((u >> 16) & 1u)) >> 16;
  return (u16)r;
}
__device__ inline float sigf(float x) { return 1.0f / (1.0f + __expf(-x)); }

// ---------------- dtype detector: bf16 inputs vs f32 inputs ----------------
__global__ void k_detect(const u16* __restrict__ raw, int* __restrict__ flag) {
  __shared__ int bad;
  if (threadIdx.x == 0) bad = 0;
  __syncthreads();
  for (int i = threadIdx.x; i < 4096; i += 256) {
    float f = b2f(raw[i]);
    if (!(fabsf(f) < 1000.0f)) atomicOr(&bad, 1);  // NaN/inf/huge -> f32 low-halves
  }
  __syncthreads();
  if (threadIdx.x == 0) *flag = bad ? 0 : 1;
}

// ---------------- convert all float inputs to f32 staging ----------------
__global__ void k_convert(Ptrs ptrs, float* __restrict__ W) {
  int gid = blockIdx.x * 256 + threadIdx.x;
  if (gid >= CVT_TOTAL) return;
  int flag = *(const int*)(W + FLAG_OFF);
  int ti = 0;
  #pragma unroll
  for (int i = 1; i < 26; ++i) ti += (gid >= d_cum[i]);
  int j = gid - d_cum[ti];
  const void* src = ptrs.p[ti];
  W[gid] = flag ? b2f(((const u16*)src)[j]) : ((const float*)src)[j];
}

// ---------------- conv1 ----------------
__global__ void k_conv1(const float* __restrict__ W, u16* __restrict__ bufX) {
  int gid = blockIdx.x * 256 + threadIdx.x;     // (n,t,h8)
  int h8 = gid & 7, t = (gid >> 3) & 15, n = gid >> 7;
  float d0 = W[F_DATA + n * 32 + t];
  float d1 = W[F_DATA + n * 32 + 16 + t];
  u32 out[4];
  #pragma unroll
  for (int jp = 0; jp < 4; ++jp) {
    int h = h8 * 8 + jp * 2;
    float v0 = fmaf(d0, W[P_W1 + h * 2],       fmaf(d1, W[P_W1 + h * 2 + 1],       W[P_B1 + h]));
    float v1 = fmaf(d0, W[P_W1 + (h + 1) * 2], fmaf(d1, W[P_W1 + (h + 1) * 2 + 1], W[P_B1 + h + 1]));
    out[jp] = (u32)f2b(v0) | ((u32)f2b(v1) << 16);
  }
  *reinterpret_cast<uint4*>(bufX + (size_t)gid * 8) = make_uint4(out[0], out[1], out[2], out[3]);
}

// ---------------- pre-swizzle MFMA B-frags (Wf, Wg1, Wg2) + WihT f/b ------
__global__ void k_preswz(float* __restrict__ W, u16* __restrict__ WfB) {
  int i = blockIdx.x * 256 + threadIdx.x;
  if (i < 61440) {
    int j = i & 7, lane = (i >> 3) & 63, kt = (i >> 9) & 3, ks = i >> 11;
    int kout = kt * 16 + (lane & 15);
    int m = ks * 32 + ((lane >> 4) << 3) + j;
    WfB[i] = f2b(W[P_WF + kout * 960 + m]);
  } else if (i < 69632) {
    int ii = i - 61440;
    int L = ii >> 12, r = ii & 4095;
    int j = r & 7, lane = (r >> 3) & 63, nt = (r >> 9) & 3, ks = (r >> 11) & 1;
    int h = ks * 32 + ((lane >> 4) << 3) + j;
    int k = nt * 16 + (lane & 15);
    WfB[i] = f2b(W[(L ? P_WG2 : P_WG1) + h * 64 + k]);
  } else if (i < 90112) {
    int e = i - 69632;
    int which = e / 10240, rem = e % 10240;
    int kk = rem / 160, jj = rem % 160;
    W[WIHT_OFF + e] = W[(which ? P_WIHB : P_WIHF) + jj * 64 + kk];
  }
}

// ---------------- fused GCN layer (one block = one graph, 4 waves, MFMA) ----
template<int LAYER>
__global__ __launch_bounds__(256, 4)
void k_gcn(const float* __restrict__ W, const int* __restrict__ ei,
           const u16* __restrict__ bufIn, u16* __restrict__ bufRes,
           u16* __restrict__ bufOut, const u16* __restrict__ WgB,
           float* __restrict__ S1, float* __restrict__ S2,
           int bgoff, int scoff, int shoff) {
  __shared__ u16 s_x[15360];     // 30720 B, swizzled [v][t][h] bf16 (byte ^= (t&7)<<4)
  __shared__ float s_m[240];     // M[vc][vr] padded rows of 16
  __shared__ float s_deg[16];
  __shared__ int s_row[40], s_col[40];

  int g = blockIdx.x, tid = threadIdx.x;
  float ew = 0.f; int er = 0, ec = 0;
  if (tid < 40) {
    er = ei[g * 40 + tid] - g * 15;
    ec = ei[NE + g * 40 + tid] - g * 15;
    ew = W[F_EA + g * 40 + tid];
    s_row[tid] = er; s_col[tid] = ec;
  }
  if (tid >= 64 && tid < 80) s_deg[tid - 64] = 1.0f;   // self-loop weight
  for (int i = tid; i < 240; i += 256) s_m[i] = 0.f;

  const u32* pin = (const u32*)(bufIn + g * 15360);
  u32* sx32 = (u32*)s_x;
  if (LAYER == 1) {
    #pragma unroll
    for (int c = 0; c < 30; ++c) {
      int i = tid + c * 256;
      int t = (i >> 5) & 15;
      sx32[(((u32)(i << 2)) ^ (((u32)(t & 7)) << 4)) >> 2] = pin[i];
    }
  } else {
    u32* pres = (u32*)(bufRes + g * 15360);
    #pragma unroll 2
    for (int c = 0; c < 30; ++c) {
      int i = tid + c * 256;
      u32 uy = pin[i], ux = pres[i];
      int th = (2 * i) & 1023;
      int t = th >> 6;
      float a = fmaf(b2f((u16)(uy & 0xffff)), W[scoff + th],     W[shoff + th])     + b2f((u16)(ux & 0xffff));
      float b = fmaf(b2f((u16)(uy >> 16)),    W[scoff + th + 1], W[shoff + th + 1]) + b2f((u16)(ux >> 16));
      u32 pk = (u32)f2b(a) | ((u32)f2b(b) << 16);
      pres[i] = pk;                                        // x1 back to global
      sx32[(((u32)(i << 2)) ^ (((u32)(t & 7)) << 4)) >> 2] = pk;
    }
  }
  __syncthreads();
  if (tid < 40) atomicAdd(&s_deg[ec], ew);
  __syncthreads();
  if (tid < 15) s_deg[tid] = rsqrtf(s_deg[tid]);
  __syncthreads();
  if (tid < 40) atomicAdd(&s_m[ec * 16 + er], s_deg[er] * ew * s_deg[ec]);
  if (tid >= 64 && tid < 80) {
    float dv = s_deg[tid - 64];
    atomicAdd(&s_m[(tid - 64) * 17], dv * dv);
  }
  __syncthreads();

  // aggregation, in place: each thread owns 4 columns (2 u32 pairs)
  {
    float x0[15], x1[15], x2[15], x3[15];
    int p0 = tid, p1 = tid + 256;
    int t0 = p0 >> 5, h0 = (2 * p0) & 63;
    int t1 = p1 >> 5, h1 = (2 * p1) & 63;
    u32 ba0 = ((u32)(t0 * 128 + h0 * 2)) ^ (((u32)(t0 & 7)) << 4);
    u32 ba1 = ((u32)(t1 * 128 + h1 * 2)) ^ (((u32)(t1 & 7)) << 4);
    #pragma unroll
    for (int v = 0; v < 15; ++v) {
      u32 ua = sx32[(ba0 + v * 2048) >> 2];
      u32 ub = sx32[(ba1 + v * 2048) >> 2];
      x0[v] = b2f((u16)(ua & 0xffff)); x1[v] = b2f((u16)(ua >> 16));
      x2[v] = b2f((u16)(ub & 0xffff)); x3[v] = b2f((u16)(ub >> 16));
    }
    #pragma unroll
    for (int vc = 0; vc < 15; ++vc) {
      float a0 = 0.f, a1 = 0.f, a2 = 0.f, a3 = 0.f;
      #pragma unroll
      for (int vr = 0; vr < 15; ++vr) {
        float m = s_m[vc * 16 + vr];
        a0 = fmaf(m, x0[vr], a0); a1 = fmaf(m, x1[vr], a1);
        a2 = fmaf(m, x2[vr], a2); a3 = fmaf(m, x3[vr], a3);
      }
      sx32[(ba0 + vc * 2048) >> 2] = (u32)f2b(a0) | ((u32)f2b(a1) << 16);
      sx32[(ba1 + vc * 2048) >> 2] = (u32)f2b(a2) | ((u32)f2b(a3) << 16);
    }
  }
  __syncthreads();

  // MFMA GEMM: y[v,t,k] = relu(agg[v,t,:] . Wg[:,k] + bg[k]); wave = n-tile
  int wid = tid >> 6, lane = tid & 63;
  int tA = lane & 15, kg = lane >> 4;
  const bf16x8* wb = (const bf16x8*)WgB;
  bf16x8 bf0 = wb[(0 * 4 + wid) * 64 + lane];
  bf16x8 bf1 = wb[(1 * 4 + wid) * 64 + lane];
  int kout = wid * 16 + tA;
  float bias = W[bgoff + kout];
  f32x4 acc[15];
  #pragma unroll
  for (int v = 0; v < 15; ++v) acc[v] = (f32x4){0.f, 0.f, 0.f, 0.f};
  u32 sw = ((u32)(tA & 7)) << 4;
  #pragma unroll
  for (int v = 0; v < 15; ++v) {
    u32 bb = (u32)(v * 2048 + tA * 128 + kg * 16);
    bf16x8 a0 = *(const bf16x8*)(s_x + ((bb ^ sw) >> 1));
    bf16x8 a1 = *(const bf16x8*)(s_x + (((bb + 64) ^ sw) >> 1));
    acc[v] = __builtin_amdgcn_mfma_f32_16x16x32_bf16(a0, bf0, acc[v], 0, 0, 0);
    acc[v] = __builtin_amdgcn_mfma_f32_16x16x32_bf16(a1, bf1, acc[v], 0, 0, 0);
  }
  float s1r[4] = {0.f, 0.f, 0.f, 0.f}, s2r[4] = {0.f, 0.f, 0.f, 0.f};
  u16* pout = bufOut + g * 15360;
  #pragma unroll
  for (int v = 0; v < 15; ++v) {
    #pragma unroll
    for (int r = 0; r < 4; ++r) {
      float y = fmaxf(acc[v][r] + bias, 0.f);
      pout[v * 1024 + (kg * 4 + r) * 64 + kout] = f2b(y);
      s1r[r] += y; s2r[r] += y * y;
    }
  }
  #pragma unroll
  for (int r = 0; r < 4; ++r) {
    int idx = (kg * 4 + r) * 64 + kout;
    atomicAdd(&S1[idx], s1r[r]);
    atomicAdd(&S2[idx], s2r[r]);
  }
}

// ---------------- finalize BN stats -> fused scale/shift ----------------
__global__ void k_finalize(float* __restrict__ W, int layer) {
  int i = blockIdx.x * 256 + threadIdx.x;
  if (i >= 1024) return;
  int base = STATS_OFF + (layer == 1 ? 0 : 2048);
  int scb  = STATS_OFF + (layer == 1 ? 4096 : 6144);
  float m   = W[base + i] * (1.0f / 30720.0f);
  float var = W[base + 1024 + i] * (1.0f / 30720.0f) - m * m;
  float istd = rsqrtf(var + 1e-5f);
  int h = i & 63;
  float gm = W[(layer == 1 ? P_G1 : P_G2) + h];
  float bt = W[(layer == 1 ? P_BE1 : P_BE2) + h];
  float sc = gm * istd;
  W[scb + i] = sc;
  W[scb + 1024 + i] = bt - m * sc;
}

// ---------------- fc1 via MFMA: Xs[t,b,k] = relu(x2[b] . Wf[k] + bf[k]) ----
__global__ __launch_bounds__(256, 4)
void k_fc1(const float* __restrict__ W, const u16* __restrict__ bufY2,
           const u16* __restrict__ bufX1, const u16* __restrict__ WfB,
           float* __restrict__ Xs) {
  __shared__ u16 s_x[15360];            // 30720 B, swizzled [v][t][h] bf16
  __shared__ float s_sc[1024], s_sh[1024];
  int g = blockIdx.x, tid = threadIdx.x;
  for (int i = tid; i < 1024; i += 256) {
    s_sc[i] = W[STATS_OFF + 6144 + i];
    s_sh[i] = W[STATS_OFF + 7168 + i];
  }
  __syncthreads();
  const u32* py = (const u32*)(bufY2 + g * 15360);
  const u32* px = (const u32*)(bufX1 + g * 15360);
  u32* sx32 = (u32*)s_x;
  for (int i = tid; i < 7680; i += 256) {
    u32 uy = py[i], ux = px[i];
    int e = 2 * i;
    int th = e & 1023;
    int t = th >> 6;
    float a = fmaf(b2f((u16)(uy & 0xffff)), s_sc[th],     s_sh[th])     + b2f((u16)(ux & 0xffff));
    float b = fmaf(b2f((u16)(uy >> 16)),    s_sc[th + 1], s_sh[th + 1]) + b2f((u16)(ux >> 16));
    u32 byte = ((u32)(e << 1)) ^ (((u32)(t & 7)) << 4);
    sx32[byte >> 2] = (u32)f2b(a) | ((u32)f2b(b) << 16);
  }
  __syncthreads();

  int wid = tid >> 6, lane = tid & 63;
  int tA = lane & 15, kg = lane >> 4;
  f32x4 acc = {0.f, 0.f, 0.f, 0.f};
  const bf16x8* wf = (const bf16x8*)WfB;
  #pragma unroll 2
  for (int ks = 0; ks < 30; ++ks) {
    int v = ks >> 1, half = ks & 1;
    u32 byte = (u32)(v * 2048 + tA * 128 + (half * 32 + kg * 8) * 2) ^ (((u32)(tA & 7)) << 4);
    bf16x8 afrag = *(const bf16x8*)(s_x + (byte >> 1));
    bf16x8 bfrag = wf[(ks * 4 + wid) * 64 + lane];
    acc = __builtin_amdgcn_mfma_f32_16x16x32_bf16(afrag, bfrag, acc, 0, 0, 0);
  }
  int kout = wid * 16 + (lane & 15);
  float bias = W[P_BF + kout];
  #pragma unroll
  for (int r = 0; r < 4; ++r) {
    int t = (lane >> 4) * 4 + r;
    Xs[t * 131072 + g * 64 + kout] = fmaxf(acc[r] + bias, 0.0f);
  }
}

// ---------------- gate-x precompute: gx = bias + Xs @ WihT -----------------
// blocks 0..1023: fwd rows R=blk*32..+31 of [t*2048+b]; 1024..1087: bwd (t=15 rows)
__global__ __launch_bounds__(256)
void k_gatex(const float* __restrict__ W, const float* __restrict__ Xs,
             float* __restrict__ gxf, float* __restrict__ gxb) {
  __shared__ float s_x[2048];     // 32 rows x 64
  __shared__ float s_w[10240];    // [kk][jj] 64 x 160
  __shared__ float s_b[160];
  int blk = blockIdx.x, tid = threadIdx.x;
  int fwd = blk < 1024;
  const float* xsrc = fwd ? (Xs + blk * 2048) : (Xs + 1966080 + (blk - 1024) * 2048);
  const float* wsrc = W + WIHT_OFF + (fwd ? 0 : 10240);
  int bo  = fwd ? P_BIHF : P_BIHB;
  int bo2 = fwd ? P_BHHF : P_BHHB;
  float* out = fwd ? (gxf + blk * 5120) : (gxb + (blk - 1024) * 5120);

  float4* sx4 = (float4*)s_x;
  const float4* xs4 = (const float4*)xsrc;
  for (int i = tid; i < 512; i += 256) sx4[i] = xs4[i];
  for (int i = tid; i < 10240; i += 256) s_w[i] = wsrc[i];
  if (tid < 160) s_b[tid] = W[bo + tid] + W[bo2 + tid];
  __syncthreads();

  int rb = (tid >> 5) * 4, c0 = tid & 31;
  float acc[4][5];
  #pragma unroll
  for (int r = 0; r < 4; ++r)
    #pragma unroll
    for (int q = 0; q < 5; ++q) acc[r][q] = s_b[c0 + 32 * q];
  #pragma unroll 4
  for (int kk = 0; kk < 64; ++kk) {
    float w0 = s_w[kk * 160 + c0],      w1 = s_w[kk * 160 + c0 + 32];
    float w2 = s_w[kk * 160 + c0 + 64], w3 = s_w[kk * 160 + c0 + 96];
    float w4 = s_w[kk * 160 + c0 + 128];
    #pragma unroll
    for (int r = 0; r < 4; ++r) {
      float xv = s_x[(rb + r) * 64 + kk];
      acc[r][0] = fmaf(xv, w0, acc[r][0]);
      acc[r][1] = fmaf(xv, w1, acc[r][1]);
      acc[r][2] = fmaf(xv, w2, acc[r][2]);
      acc[r][3] = fmaf(xv, w3, acc[r][3]);
      acc[r][4] = fmaf(xv, w4, acc[r][4]);
    }
  }
  #pragma unroll
  for (int r = 0; r < 4; ++r)
    #pragma unroll
    for (int q = 0; q < 5; ++q)
      out[(rb + r) * 160 + c0 + 32 * q] = acc[r][q];
}

// ---------------- recurrent LSTM (h-part only) + bwd nonlin + classifier ---
// 512 thr = 8 waves; wave r owns batch row r0+r. Gates per lane: l, l+64, (+128 if l<32).
__global__ __launch_bounds__(512)
void k_lstm2(const float* __restrict__ W, const float* __restrict__ gxf,
             const float* __restrict__ gxb, void* __restrict__ dout,
             const int* __restrict__ flagp) {
  __shared__ float s_whh[40 * 162];   // [kk][jj] pad 162 (conflict-free reads)
  __shared__ float s_h[320], s_c[320], s_hb[320];
  __shared__ float s_g[1280];
  __shared__ float s_cls[128];
  int tid = threadIdx.x, r0 = blockIdx.x * 8;

  for (int i = tid; i < 6400; i += 512) {
    int jj = i / 40, kk = i % 40;       // coalesced global read, scattered LDS write
    s_whh[kk * 162 + jj] = W[P_WHHF + i];
  }
  if (tid < 320) { s_h[tid] = 0.f; s_c[tid] = 0.f; }
  __syncthreads();

  int r = tid >> 6, l = tid & 63;
  int l2 = (l < 32) ? l + 128 : l;      // safe duplicate for l>=32
  const float* gbase = gxf + (r0 + r) * 160;
  float g0 = gbase[l], g1 = gbase[l + 64], g2 = gbase[l2];

  for (int t = 0; t < 16; ++t) {
    float acc0 = g0, acc1 = g1, acc2 = g2;
    int tn = (t < 15) ? t + 1 : 15;
    const float* gnext = gbase + tn * 327680;
    g0 = gnext[l]; g1 = gnext[l + 64]; g2 = gnext[l2];   // prefetch next step
    const float* hr = s_h + r * 40;
    #pragma unroll 8
    for (int kk = 0; kk < 40; ++kk) {
      float hv = hr[kk];
      acc0 = fmaf(hv, s_whh[kk * 162 + l], acc0);
      acc1 = fmaf(hv, s_whh[kk * 162 + l + 64], acc1);
      acc2 = fmaf(hv, s_whh[kk * 162 + l2], acc2);
    }
    s_g[r * 160 + l] = acc0;
    s_g[r * 160 + l + 64] = acc1;
    if (l < 32) s_g[r * 160 + l2] = acc2;
    __syncthreads();
    if (tid < 320) {
      int row = tid / 40, jj = tid % 40;
      const float* gr = s_g + row * 160;
      float ig = gr[jj], fg = gr[jj + 40], gg = gr[jj + 80], og = gr[jj + 120];
      float c = sigf(fg) * s_c[tid] + sigf(ig) * tanhf(gg);
      s_c[tid] = c;
      s_h[tid] = sigf(og) * tanhf(c);
    }
    __syncthreads();
  }

  // bwd LSTM first step from zero state: pure nonlinearity on gxb
  if (tid < 320) {
    int row = tid / 40, jj = tid % 40;
    const float* gb = gxb + (r0 + row) * 160;
    float ig = gb[jj], gg = gb[jj + 80], og = gb[jj + 120];
    float c = sigf(ig) * tanhf(gg);
    s_hb[tid] = sigf(og) * tanhf(c);
  }
  __syncthreads();

  // classifier: relu([h_f|h_b] @ Wc1^T + bc1) @ Wc2^T + bc2
  if (tid < 128) {
    int rr = tid >> 4, jj = tid & 15;
    float a = W[P_BC1 + jj];
    for (int p = 0; p < 40; ++p) a = fmaf(W[P_WC1 + jj * 80 + p],      s_h[rr * 40 + p],  a);
    for (int p = 0; p < 40; ++p) a = fmaf(W[P_WC1 + jj * 80 + 40 + p], s_hb[rr * 40 + p], a);
    s_cls[rr * 16 + jj] = fmaxf(a, 0.0f);
  }
  __syncthreads();
  if (tid < 8) {
    float o = W[P_BC2];
    #pragma unroll
    for (int jj = 0; jj < 16; ++jj) o = fmaf(W[P_WC2 + jj], s_cls[tid * 16 + jj], o);
    if (*flagp) ((u16*)dout)[r0 + tid] = f2b(o);
    else        ((float*)dout)[r0 + tid] = o;
  }
}

// ---------------- launch ----------------
extern "C" void kernel_launch(void* const* d_in, const int* in_sizes, int n_in,
                              void* d_out, int out_size, void* d_ws, size_t ws_size,
                              hipStream_t stream) {
  float* W = (float*)d_ws;
  u16* bufX = (u16*)((char*)d_ws + BUFX_BYTE);
  u16* bufY = (u16*)((char*)d_ws + BUFY_BYTE);
  u16* WfB  = (u16*)(W + WFB_OFF);
  float* gxf = (float*)((char*)d_ws + BUFX_BYTE);   // reuses bufX after fc1
  float* gxb = gxf + 5242880;
  const int* ei = (const int*)d_in[26];

  hipMemsetAsync(W + STATS_OFF, 0, 4096 * sizeof(float), stream);
  k_detect<<<1, 256, 0, stream>>>((const u16*)d_in[0], (int*)(W + FLAG_OFF));
  Ptrs ptrs;
  for (int i = 0; i < 26; ++i) ptrs.p[i] = d_in[i];
  k_convert<<<(CVT_TOTAL + 255) / 256, 256, 0, stream>>>(ptrs, W);
  k_preswz<<<352, 256, 0, stream>>>(W, WfB);
  k_conv1<<<NN * 16 * 8 / 256, 256, 0, stream>>>(W, bufX);
  k_gcn<1><<<NB, 256, 0, stream>>>(W, ei, bufX, nullptr, bufY, WfB + 61440,
      W + STATS_OFF, W + STATS_OFF + 1024, P_BG1, 0, 0);
  k_finalize<<<4, 256, 0, stream>>>(W, 1);
  k_gcn<2><<<NB, 256, 0, stream>>>(W, ei, bufY, bufX, bufY, WfB + 65536,
      W + STATS_OFF + 2048, W + STATS_OFF + 3072, P_BG2,
      STATS_OFF + 4096, STATS_OFF + 5120);
  k_finalize<<<4, 256, 0, stream>>>(W, 2);
  k_fc1<<<NB, 256, 0, stream>>>(W, bufY, bufX, WfB, W + XS_OFF);
  k_gatex<<<1088, 256, 0, stream>>>(W, W + XS_OFF, gxf, gxb);
  k_lstm2<<<256, 512, 0, stream>>>(W, gxf, gxb, d_out, (const int*)(W + FLAG_OFF));
}

// Round 6
// 340.715 us; speedup vs baseline: 3.8188x; 1.1079x over previous
//
#include <hip/hip_runtime.h>

typedef unsigned int u32;
typedef unsigned short u16;
typedef __attribute__((ext_vector_type(8))) short bf16x8;
typedef __attribute__((ext_vector_type(4))) float f32x4;

// ---------------- problem constants ----------------
#define NB   2048
#define NV   15
#define NT   16
#define NH   64
#define NLH  40
#define EPER 40
#define NN   (NB*NV)       // 30720
#define NE   (NB*EPER)     // 81920

// ---------------- ws layout (float-element offsets unless noted) ----------------
#define F_DATA 0
#define F_EA   983040
#define P_W1   1064960
#define P_B1   1065088
#define P_WG1  1065152
#define P_BG1  1069248
#define P_G1   1069312
#define P_BE1  1069376
#define P_WG2  1069440
#define P_BG2  1073536
#define P_G2   1073600
#define P_BE2  1073664
#define P_WF   1073728
#define P_BF   1135168
#define P_WIHF 1135232
#define P_WHHF 1145472
#define P_BIHF 1151872
#define P_BHHF 1152032
#define P_WIHB 1152192
#define P_WHHB 1162432
#define P_BIHB 1168832
#define P_BHHB 1168992
#define P_WC1  1169152
#define P_BC1  1170432
#define P_WC2  1170448
#define P_BC2  1170464
#define CVT_TOTAL 1170465
#define WFB_OFF   1170496   // u16 frags: WfB[61440] ++ WgB1[4096] ++ WgB2[4096]
#define WIHT_OFF  1205504   // f32 WihT_f[64][160] ++ WihT_b[64][160]
#define STATS_OFF 1231936   // S1a,S2a,S1b,S2b,SC1,SH1,SC2,SH2 (8*1024)
#define XS_OFF    1240128   // Xs [16][2048][64] f32
#define FLAG_OFF  3337280   // int flag (1 = inputs are bf16)
#define BUFX_BYTE 13349376  // bf16 [NN][1024]: y2; later gxf/gxb f32
#define BUFY_BYTE 76263936  // bf16 [NN][1024]: y1

__device__ const int d_cum[27] = {
  0, 983040, 1064960, 1065088, 1065152, 1069248, 1069312, 1069376,
  1069440, 1073536, 1073600, 1073664, 1073728, 1135168, 1135232, 1145472,
  1151872, 1152032, 1152192, 1162432, 1168832, 1168992, 1169152, 1170432,
  1170448, 1170464, 1170465};

struct Ptrs { const void* p[26]; };

__device__ inline float b2f(u16 u) { return __uint_as_float(((u32)u) << 16); }
__device__ inline u16 f2b(float f) {
  u32 u = __float_as_uint(f);
  u32 r = (u + 0x7FFFu + ((u >> 16) & 1u)) >> 16;
  return (u16)r;
}
__device__ inline float sigf(float x) { return 1.0f / (1.0f + __expf(-x)); }

// ---------------- dtype detector ----------------
__global__ void k_detect(const u16* __restrict__ raw, int* __restrict__ flag) {
  __shared__ int bad;
  if (threadIdx.x == 0) bad = 0;
  __syncthreads();
  for (int i = threadIdx.x; i < 4096; i += 256) {
    float f = b2f(raw[i]);
    if (!(fabsf(f) < 1000.0f)) atomicOr(&bad, 1);
  }
  __syncthreads();
  if (threadIdx.x == 0) *flag = bad ? 0 : 1;
}

// ---------------- convert all float inputs to f32 staging ----------------
__global__ void k_convert(Ptrs ptrs, float* __restrict__ W) {
  int gid = blockIdx.x * 256 + threadIdx.x;
  if (gid >= CVT_TOTAL) return;
  int flag = *(const int*)(W + FLAG_OFF);
  int ti = 0;
  #pragma unroll
  for (int i = 1; i < 26; ++i) ti += (gid >= d_cum[i]);
  int j = gid - d_cum[ti];
  const void* src = ptrs.p[ti];
  W[gid] = flag ? b2f(((const u16*)src)[j]) : ((const float*)src)[j];
}

// ---------------- pre-swizzle MFMA B-frags (Wf, Wg1, Wg2) + WihT f/b ------
__global__ void k_preswz(float* __restrict__ W, u16* __restrict__ WfB) {
  int i = blockIdx.x * 256 + threadIdx.x;
  if (i < 61440) {
    int j = i & 7, lane = (i >> 3) & 63, kt = (i >> 9) & 3, ks = i >> 11;
    int kout = kt * 16 + (lane & 15);
    int m = ks * 32 + ((lane >> 4) << 3) + j;
    WfB[i] = f2b(W[P_WF + kout * 960 + m]);
  } else if (i < 69632) {
    int ii = i - 61440;
    int L = ii >> 12, r = ii & 4095;
    int j = r & 7, lane = (r >> 3) & 63, nt = (r >> 9) & 3, ks = (r >> 11) & 1;
    int h = ks * 32 + ((lane >> 4) << 3) + j;
    int k = nt * 16 + (lane & 15);
    WfB[i] = f2b(W[(L ? P_WG2 : P_WG1) + h * 64 + k]);
  } else if (i < 90112) {
    int e = i - 69632;
    int which = e / 10240, rem = e % 10240;
    int kk = rem / 160, jj = rem % 160;
    W[WIHT_OFF + e] = W[(which ? P_WIHB : P_WIHF) + jj * 64 + kk];
  }
}

// ---------------- fused GCN layer (1 block = 1 graph, 4 waves, MFMA) -------
// conv1-x recomputed in-LDS from data (no x in HBM). LAYER==2 additionally
// reads y1, builds x1=bn1(y1)+x in LDS only (no x1 in HBM), outputs y2.
template<int LAYER>
__global__ __launch_bounds__(256, 4)
void k_gcn(const float* __restrict__ W, const int* __restrict__ ei,
           const u16* __restrict__ bufIn, u16* __restrict__ bufOut,
           const u16* __restrict__ WgB,
           float* __restrict__ S1, float* __restrict__ S2,
           int bgoff, int scoff, int shoff) {
  __shared__ u16 s_x[15360];     // 30720 B, swizzled [v][t][h] bf16 (byte ^= (t&7)<<4)
  __shared__ float s_m[240];
  __shared__ float s_deg[16];
  __shared__ float s_d[480];     // data slice [v][f][t]
  __shared__ float s_w1[192];    // W1 [64][2] ++ b1 [64]

  int g = blockIdx.x, tid = threadIdx.x;
  float ew = 0.f; int er = 0, ec = 0;
  if (tid < 40) {
    er = ei[g * 40 + tid] - g * 15;
    ec = ei[NE + g * 40 + tid] - g * 15;
    ew = W[F_EA + g * 40 + tid];
  }
  if (tid >= 40 && tid < 56) s_deg[tid - 40] = 1.0f;   // self-loop weight
  for (int i = tid; i < 240; i += 256) s_m[i] = 0.f;
  if (tid >= 64 && tid < 184) ((float4*)s_d)[tid - 64] = ((const float4*)(W + F_DATA + g * 480))[tid - 64];
  if (tid >= 192 && tid < 240) ((float4*)s_w1)[tid - 192] = ((const float4*)(W + P_W1))[tid - 192];
  __syncthreads();

  if (tid < 40) atomicAdd(&s_deg[ec], ew);
  // staging: x (L1) or x1=bn1(y1)+x (L2), bf16-swizzled into LDS
  for (int i = tid; i < 1920; i += 256) {
    int v = i >> 7, rem = i & 127, t = rem >> 3, q = rem & 7;
    int h0 = q * 8;
    float d0 = s_d[v * 32 + t], d1 = s_d[v * 32 + 16 + t];
    u32 pk[4];
    if (LAYER == 1) {
      #pragma unroll
      for (int jp = 0; jp < 4; ++jp) {
        int h = h0 + jp * 2;
        float xa = fmaf(d0, s_w1[2 * h],     fmaf(d1, s_w1[2 * h + 1], s_w1[128 + h]));
        float xb = fmaf(d0, s_w1[2 * h + 2], fmaf(d1, s_w1[2 * h + 3], s_w1[129 + h]));
        pk[jp] = (u32)f2b(xa) | ((u32)f2b(xb) << 16);
      }
    } else {
      uint4 uy = ((const uint4*)(bufIn + g * 15360))[i];
      u32 uys[4] = {uy.x, uy.y, uy.z, uy.w};
      int th0 = t * 64 + h0;
      float4 A0 = *(const float4*)(W + scoff + th0), A1 = *(const float4*)(W + scoff + th0 + 4);
      float4 B0 = *(const float4*)(W + shoff + th0), B1 = *(const float4*)(W + shoff + th0 + 4);
      float scs[8] = {A0.x, A0.y, A0.z, A0.w, A1.x, A1.y, A1.z, A1.w};
      float shs[8] = {B0.x, B0.y, B0.z, B0.w, B1.x, B1.y, B1.z, B1.w};
      #pragma unroll
      for (int jp = 0; jp < 4; ++jp) {
        int j0 = jp * 2, h = h0 + j0;
        float xa = fmaf(d0, s_w1[2 * h],     fmaf(d1, s_w1[2 * h + 1], s_w1[128 + h]));
        float xb = fmaf(d0, s_w1[2 * h + 2], fmaf(d1, s_w1[2 * h + 3], s_w1[129 + h]));
        float a = fmaf(b2f((u16)(uys[jp] & 0xffff)), scs[j0],     shs[j0])     + xa;
        float b = fmaf(b2f((u16)(uys[jp] >> 16)),    scs[j0 + 1], shs[j0 + 1]) + xb;
        pk[jp] = (u32)f2b(a) | ((u32)f2b(b) << 16);
      }
    }
    u32 byte = ((u32)(i * 16)) ^ (((u32)(t & 7)) << 4);
    *(uint4*)((char*)s_x + byte) = make_uint4(pk[0], pk[1], pk[2], pk[3]);
  }
  __syncthreads();
  if (tid < 15) s_deg[tid] = rsqrtf(s_deg[tid]);
  __syncthreads();
  if (tid < 40) atomicAdd(&s_m[ec * 16 + er], s_deg[er] * ew * s_deg[ec]);
  if (tid >= 64 && tid < 80) {
    float dv = s_deg[tid - 64];
    atomicAdd(&s_m[(tid - 64) * 17], dv * dv);
  }
  __syncthreads();

  // aggregation, in place: each thread owns 4 columns (2 u32 pairs)
  u32* sx32 = (u32*)s_x;
  {
    float x0[15], x1[15], x2[15], x3[15];
    int p0 = tid, p1 = tid + 256;
    int t0 = p0 >> 5, h0 = (2 * p0) & 63;
    int t1 = p1 >> 5, h1 = (2 * p1) & 63;
    u32 ba0 = ((u32)(t0 * 128 + h0 * 2)) ^ (((u32)(t0 & 7)) << 4);
    u32 ba1 = ((u32)(t1 * 128 + h1 * 2)) ^ (((u32)(t1 & 7)) << 4);
    #pragma unroll
    for (int v = 0; v < 15; ++v) {
      u32 ua = sx32[(ba0 + v * 2048) >> 2];
      u32 ub = sx32[(ba1 + v * 2048) >> 2];
      x0[v] = b2f((u16)(ua & 0xffff)); x1[v] = b2f((u16)(ua >> 16));
      x2[v] = b2f((u16)(ub & 0xffff)); x3[v] = b2f((u16)(ub >> 16));
    }
    #pragma unroll
    for (int vc = 0; vc < 15; ++vc) {
      float a0 = 0.f, a1 = 0.f, a2 = 0.f, a3 = 0.f;
      #pragma unroll
      for (int vr = 0; vr < 15; ++vr) {
        float m = s_m[vc * 16 + vr];
        a0 = fmaf(m, x0[vr], a0); a1 = fmaf(m, x1[vr], a1);
        a2 = fmaf(m, x2[vr], a2); a3 = fmaf(m, x3[vr], a3);
      }
      sx32[(ba0 + vc * 2048) >> 2] = (u32)f2b(a0) | ((u32)f2b(a1) << 16);
      sx32[(ba1 + vc * 2048) >> 2] = (u32)f2b(a2) | ((u32)f2b(a3) << 16);
    }
  }
  __syncthreads();

  // MFMA GEMM: y[v,t,k] = relu(agg[v,t,:] . Wg[:,k] + bg[k]); wave = n-tile
  int wid = tid >> 6, lane = tid & 63;
  int tA = lane & 15, kg = lane >> 4;
  const bf16x8* wb = (const bf16x8*)WgB;
  bf16x8 bf0 = wb[(0 * 4 + wid) * 64 + lane];
  bf16x8 bf1 = wb[(1 * 4 + wid) * 64 + lane];
  int kout = wid * 16 + tA;
  float bias = W[bgoff + kout];
  f32x4 acc[15];
  #pragma unroll
  for (int v = 0; v < 15; ++v) acc[v] = (f32x4){0.f, 0.f, 0.f, 0.f};
  u32 sw = ((u32)(tA & 7)) << 4;
  #pragma unroll
  for (int v = 0; v < 15; ++v) {
    u32 bb = (u32)(v * 2048 + tA * 128 + kg * 16);
    bf16x8 a0 = *(const bf16x8*)(s_x + ((bb ^ sw) >> 1));
    bf16x8 a1 = *(const bf16x8*)(s_x + (((bb + 64) ^ sw) >> 1));
    acc[v] = __builtin_amdgcn_mfma_f32_16x16x32_bf16(a0, bf0, acc[v], 0, 0, 0);
    acc[v] = __builtin_amdgcn_mfma_f32_16x16x32_bf16(a1, bf1, acc[v], 0, 0, 0);
  }
  float s1r[4] = {0.f, 0.f, 0.f, 0.f}, s2r[4] = {0.f, 0.f, 0.f, 0.f};
  u16* pout = bufOut + g * 15360;
  #pragma unroll
  for (int v = 0; v < 15; ++v) {
    #pragma unroll
    for (int r = 0; r < 4; ++r) {
      float y = fmaxf(acc[v][r] + bias, 0.f);
      pout[v * 1024 + (kg * 4 + r) * 64 + kout] = f2b(y);
      s1r[r] += y; s2r[r] += y * y;
    }
  }
  #pragma unroll
  for (int r = 0; r < 4; ++r) {
    int idx = (kg * 4 + r) * 64 + kout;
    atomicAdd(&S1[idx], s1r[r]);
    atomicAdd(&S2[idx], s2r[r]);
  }
}

// ---------------- finalize BN stats -> fused scale/shift ----------------
__global__ void k_finalize(float* __restrict__ W, int layer) {
  int i = blockIdx.x * 256 + threadIdx.x;
  if (i >= 1024) return;
  int base = STATS_OFF + (layer == 1 ? 0 : 2048);
  int scb  = STATS_OFF + (layer == 1 ? 4096 : 6144);
  float m   = W[base + i] * (1.0f / 30720.0f);
  float var = W[base + 1024 + i] * (1.0f / 30720.0f) - m * m;
  float istd = rsqrtf(var + 1e-5f);
  int h = i & 63;
  float gm = W[(layer == 1 ? P_G1 : P_G2) + h];
  float bt = W[(layer == 1 ? P_BE1 : P_BE2) + h];
  float sc = gm * istd;
  W[scb + i] = sc;
  W[scb + 1024 + i] = bt - m * sc;
}

// ---------------- fc1 via MFMA: in = bn2(y2)+bn1(y1)+x(recomputed) ---------
__global__ __launch_bounds__(256, 4)
void k_fc1(const float* __restrict__ W, const u16* __restrict__ bufY2,
           const u16* __restrict__ bufY1, const u16* __restrict__ WfB,
           float* __restrict__ Xs) {
  __shared__ u16 s_x[15360];
  __shared__ float s_d[480];
  __shared__ float s_w1[192];
  int g = blockIdx.x, tid = threadIdx.x;
  if (tid < 120) ((float4*)s_d)[tid] = ((const float4*)(W + F_DATA + g * 480))[tid];
  if (tid >= 128 && tid < 176) ((float4*)s_w1)[tid - 128] = ((const float4*)(W + P_W1))[tid - 128];
  __syncthreads();
  const uint4* py2 = (const uint4*)(bufY2 + g * 15360);
  const uint4* py1 = (const uint4*)(bufY1 + g * 15360);
  for (int i = tid; i < 1920; i += 256) {
    int v = i >> 7, rem = i & 127, t = rem >> 3, q = rem & 7;
    int h0 = q * 8, th0 = t * 64 + h0;
    uint4 u2 = py2[i], u1 = py1[i];
    u32 u2s[4] = {u2.x, u2.y, u2.z, u2.w}, u1s[4] = {u1.x, u1.y, u1.z, u1.w};
    float d0 = s_d[v * 32 + t], d1 = s_d[v * 32 + 16 + t];
    float4 A0 = *(const float4*)(W + STATS_OFF + 6144 + th0), A1 = *(const float4*)(W + STATS_OFF + 6148 + th0);
    float4 B0 = *(const float4*)(W + STATS_OFF + 7168 + th0), B1 = *(const float4*)(W + STATS_OFF + 7172 + th0);
    float4 C0 = *(const float4*)(W + STATS_OFF + 4096 + th0), C1 = *(const float4*)(W + STATS_OFF + 4100 + th0);
    float4 D0 = *(const float4*)(W + STATS_OFF + 5120 + th0), D1 = *(const float4*)(W + STATS_OFF + 5124 + th0);
    float sc2[8] = {A0.x, A0.y, A0.z, A0.w, A1.x, A1.y, A1.z, A1.w};
    float sh2[8] = {B0.x, B0.y, B0.z, B0.w, B1.x, B1.y, B1.z, B1.w};
    float sc1[8] = {C0.x, C0.y, C0.z, C0.w, C1.x, C1.y, C1.z, C1.w};
    float sh1[8] = {D0.x, D0.y, D0.z, D0.w, D1.x, D1.y, D1.z, D1.w};
    u32 pk[4];
    #pragma unroll
    for (int jp = 0; jp < 4; ++jp) {
      int j0 = jp * 2, h = h0 + j0;
      float xa = fmaf(d0, s_w1[2 * h],     fmaf(d1, s_w1[2 * h + 1], s_w1[128 + h]));
      float xb = fmaf(d0, s_w1[2 * h + 2], fmaf(d1, s_w1[2 * h + 3], s_w1[129 + h]));
      float x1a = fmaf(b2f((u16)(u1s[jp] & 0xffff)), sc1[j0],     sh1[j0])     + xa;
      float x1b = fmaf(b2f((u16)(u1s[jp] >> 16)),    sc1[j0 + 1], sh1[j0 + 1]) + xb;
      float a = fmaf(b2f((u16)(u2s[jp] & 0xffff)), sc2[j0],     sh2[j0])     + x1a;
      float b = fmaf(b2f((u16)(u2s[jp] >> 16)),    sc2[j0 + 1], sh2[j0 + 1]) + x1b;
      pk[jp] = (u32)f2b(a) | ((u32)f2b(b) << 16);
    }
    u32 byte = ((u32)(i * 16)) ^ (((u32)(t & 7)) << 4);
    *(uint4*)((char*)s_x + byte) = make_uint4(pk[0], pk[1], pk[2], pk[3]);
  }
  __syncthreads();

  int wid = tid >> 6, lane = tid & 63;
  int tA = lane & 15, kg = lane >> 4;
  f32x4 acc = {0.f, 0.f, 0.f, 0.f};
  const bf16x8* wf = (const bf16x8*)WfB;
  #pragma unroll 2
  for (int ks = 0; ks < 30; ++ks) {
    int v = ks >> 1, half = ks & 1;
    u32 byte = (u32)(v * 2048 + tA * 128 + (half * 32 + kg * 8) * 2) ^ (((u32)(tA & 7)) << 4);
    bf16x8 afrag = *(const bf16x8*)(s_x + (byte >> 1));
    bf16x8 bfrag = wf[(ks * 4 + wid) * 64 + lane];
    acc = __builtin_amdgcn_mfma_f32_16x16x32_bf16(afrag, bfrag, acc, 0, 0, 0);
  }
  int kout = wid * 16 + (lane & 15);
  float bias = W[P_BF + kout];
  #pragma unroll
  for (int r = 0; r < 4; ++r) {
    int t = (lane >> 4) * 4 + r;
    Xs[t * 131072 + g * 64 + kout] = fmaxf(acc[r] + bias, 0.0f);
  }
}

// ---------------- gate-x precompute: gx = bias + Xs @ WihT -----------------
__global__ __launch_bounds__(256)
void k_gatex(const float* __restrict__ W, const float* __restrict__ Xs,
             float* __restrict__ gxf, float* __restrict__ gxb) {
  __shared__ float s_x[2048];
  __shared__ float s_w[10240];
  __shared__ float s_b[160];
  int blk = blockIdx.x, tid = threadIdx.x;
  int fwd = blk < 1024;
  const float* xsrc = fwd ? (Xs + blk * 2048) : (Xs + 1966080 + (blk - 1024) * 2048);
  const float* wsrc = W + WIHT_OFF + (fwd ? 0 : 10240);
  int bo  = fwd ? P_BIHF : P_BIHB;
  int bo2 = fwd ? P_BHHF : P_BHHB;
  float* out = fwd ? (gxf + blk * 5120) : (gxb + (blk - 1024) * 5120);

  float4* sx4 = (float4*)s_x;
  const float4* xs4 = (const float4*)xsrc;
  for (int i = tid; i < 512; i += 256) sx4[i] = xs4[i];
  for (int i = tid; i < 10240; i += 256) s_w[i] = wsrc[i];
  if (tid < 160) s_b[tid] = W[bo + tid] + W[bo2 + tid];
  __syncthreads();

  int rb = (tid >> 5) * 4, c0 = tid & 31;
  float acc[4][5];
  #pragma unroll
  for (int r = 0; r < 4; ++r)
    #pragma unroll
    for (int q = 0; q < 5; ++q) acc[r][q] = s_b[c0 + 32 * q];
  #pragma unroll 4
  for (int kk = 0; kk < 64; ++kk) {
    float w0 = s_w[kk * 160 + c0],      w1 = s_w[kk * 160 + c0 + 32];
    float w2 = s_w[kk * 160 + c0 + 64], w3 = s_w[kk * 160 + c0 + 96];
    float w4 = s_w[kk * 160 + c0 + 128];
    #pragma unroll
    for (int r = 0; r < 4; ++r) {
      float xv = s_x[(rb + r) * 64 + kk];
      acc[r][0] = fmaf(xv, w0, acc[r][0]);
      acc[r][1] = fmaf(xv, w1, acc[r][1]);
      acc[r][2] = fmaf(xv, w2, acc[r][2]);
      acc[r][3] = fmaf(xv, w3, acc[r][3]);
      acc[r][4] = fmaf(xv, w4, acc[r][4]);
    }
  }
  #pragma unroll
  for (int r = 0; r < 4; ++r)
    #pragma unroll
    for (int q = 0; q < 5; ++q)
      out[(rb + r) * 160 + c0 + 32 * q] = acc[r][q];
}

// ---------------- recurrent LSTM (h-part only) + bwd nonlin + classifier ---
__global__ __launch_bounds__(512)
void k_lstm2(const float* __restrict__ W, const float* __restrict__ gxf,
             const float* __restrict__ gxb, void* __restrict__ dout,
             const int* __restrict__ flagp) {
  __shared__ float s_whh[40 * 162];
  __shared__ float s_h[320], s_c[320], s_hb[320];
  __shared__ float s_g[1280];
  __shared__ float s_cls[128];
  int tid = threadIdx.x, r0 = blockIdx.x * 8;

  for (int i = tid; i < 6400; i += 512) {
    int jj = i / 40, kk = i % 40;
    s_whh[kk * 162 + jj] = W[P_WHHF + i];
  }
  if (tid < 320) { s_h[tid] = 0.f; s_c[tid] = 0.f; }
  __syncthreads();

  int r = tid >> 6, l = tid & 63;
  int l2 = (l < 32) ? l + 128 : l;
  const float* gbase = gxf + (r0 + r) * 160;
  float g0 = gbase[l], g1 = gbase[l + 64], g2 = gbase[l2];

  for (int t = 0; t < 16; ++t) {
    float acc0 = g0, acc1 = g1, acc2 = g2;
    int tn = (t < 15) ? t + 1 : 15;
    const float* gnext = gbase + tn * 327680;
    g0 = gnext[l]; g1 = gnext[l + 64]; g2 = gnext[l2];
    const float* hr = s_h + r * 40;
    #pragma unroll 8
    for (int kk = 0; kk < 40; ++kk) {
      float hv = hr[kk];
      acc0 = fmaf(hv, s_whh[kk * 162 + l], acc0);
      acc1 = fmaf(hv, s_whh[kk * 162 + l + 64], acc1);
      acc2 = fmaf(hv, s_whh[kk * 162 + l2], acc2);
    }
    s_g[r * 160 + l] = acc0;
    s_g[r * 160 + l + 64] = acc1;
    if (l < 32) s_g[r * 160 + l2] = acc2;
    __syncthreads();
    if (tid < 320) {
      int row = tid / 40, jj = tid % 40;
      const float* gr = s_g + row * 160;
      float ig = gr[jj], fg = gr[jj + 40], gg = gr[jj + 80], og = gr[jj + 120];
      float c = sigf(fg) * s_c[tid] + sigf(ig) * tanhf(gg);
      s_c[tid] = c;
      s_h[tid] = sigf(og) * tanhf(c);
    }
    __syncthreads();
  }

  if (tid < 320) {
    int row = tid / 40, jj = tid % 40;
    const float* gb = gxb + (r0 + row) * 160;
    float ig = gb[jj], gg = gb[jj + 80], og = gb[jj + 120];
    float c = sigf(ig) * tanhf(gg);
    s_hb[tid] = sigf(og) * tanhf(c);
  }
  __syncthreads();

  if (tid < 128) {
    int rr = tid >> 4, jj = tid & 15;
    float a = W[P_BC1 + jj];
    for (int p = 0; p < 40; ++p) a = fmaf(W[P_WC1 + jj * 80 + p],      s_h[rr * 40 + p],  a);
    for (int p = 0; p < 40; ++p) a = fmaf(W[P_WC1 + jj * 80 + 40 + p], s_hb[rr * 40 + p], a);
    s_cls[rr * 16 + jj] = fmaxf(a, 0.0f);
  }
  __syncthreads();
  if (tid < 8) {
    float o = W[P_BC2];
    #pragma unroll
    for (int jj = 0; jj < 16; ++jj) o = fmaf(W[P_WC2 + jj], s_cls[tid * 16 + jj], o);
    if (*flagp) ((u16*)dout)[r0 + tid] = f2b(o);
    else        ((float*)dout)[r0 + tid] = o;
  }
}

// ---------------- launch ----------------
extern "C" void kernel_launch(void* const* d_in, const int* in_sizes, int n_in,
                              void* d_out, int out_size, void* d_ws, size_t ws_size,
                              hipStream_t stream) {
  float* W = (float*)d_ws;
  u16* bufX = (u16*)((char*)d_ws + BUFX_BYTE);   // y2
  u16* bufY = (u16*)((char*)d_ws + BUFY_BYTE);   // y1
  u16* WfB  = (u16*)(W + WFB_OFF);
  float* gxf = (float*)((char*)d_ws + BUFX_BYTE);   // reuses y2 region after fc1
  float* gxb = gxf + 5242880;
  const int* ei = (const int*)d_in[26];

  hipMemsetAsync(W + STATS_OFF, 0, 4096 * sizeof(float), stream);
  k_detect<<<1, 256, 0, stream>>>((const u16*)d_in[0], (int*)(W + FLAG_OFF));
  Ptrs ptrs;
  for (int i = 0; i < 26; ++i) ptrs.p[i] = d_in[i];
  k_convert<<<(CVT_TOTAL + 255) / 256, 256, 0, stream>>>(ptrs, W);
  k_preswz<<<352, 256, 0, stream>>>(W, WfB);
  k_gcn<1><<<NB, 256, 0, stream>>>(W, ei, nullptr, bufY, WfB + 61440,
      W + STATS_OFF, W + STATS_OFF + 1024, P_BG1, 0, 0);
  k_finalize<<<4, 256, 0, stream>>>(W, 1);
  k_gcn<2><<<NB, 256, 0, stream>>>(W, ei, bufY, bufX, WfB + 65536,
      W + STATS_OFF + 2048, W + STATS_OFF + 3072, P_BG2,
      STATS_OFF + 4096, STATS_OFF + 5120);
  k_finalize<<<4, 256, 0, stream>>>(W, 2);
  k_fc1<<<NB, 256, 0, stream>>>(W, bufX, bufY, WfB, W + XS_OFF);
  k_gatex<<<1088, 256, 0, stream>>>(W, W + XS_OFF, gxf, gxb);
  k_lstm2<<<256, 512, 0, stream>>>(W, gxf, gxb, d_out, (const int*)(W + FLAG_OFF));
}

// Round 7
// 336.977 us; speedup vs baseline: 3.8612x; 1.0111x over previous
//
#include <hip/hip_runtime.h>

typedef unsigned int u32;
typedef unsigned short u16;
typedef __attribute__((ext_vector_type(8))) short bf16x8;
typedef __attribute__((ext_vector_type(4))) float f32x4;

// ---------------- problem constants ----------------
#define NB   2048
#define NV   15
#define NT   16
#define NH   64
#define NLH  40
#define EPER 40
#define NN   (NB*NV)       // 30720
#define NE   (NB*EPER)     // 81920

// ---------------- ws layout (float-element offsets unless noted) ----------------
#define F_DATA 0
#define F_EA   983040
#define P_W1   1064960
#define P_B1   1065088
#define P_WG1  1065152
#define P_BG1  1069248
#define P_G1   1069312
#define P_BE1  1069376
#define P_WG2  1069440
#define P_BG2  1073536
#define P_G2   1073600
#define P_BE2  1073664
#define P_WF   1073728
#define P_BF   1135168
#define P_WIHF 1135232
#define P_WHHF 1145472
#define P_BIHF 1151872
#define P_BHHF 1152032
#define P_WIHB 1152192
#define P_WHHB 1162432
#define P_BIHB 1168832
#define P_BHHB 1168992
#define P_WC1  1169152
#define P_BC1  1170432
#define P_WC2  1170448
#define P_BC2  1170464
#define CVT_TOTAL 1170465
#define WFB_OFF   1170496   // u16 frags: WfB[61440] ++ WgB1[4096] ++ WgB2[4096]
#define WIHT_OFF  1205504   // f32 WihT_f[64][160] ++ WihT_b[64][160]
#define STATS_OFF 1231936   // S1a,S2a,S1b,S2b,SC1,SH1,SC2,SH2 (8*1024)
#define XS_OFF    1240128   // Xs [16][2048][64] f32
#define FLAG_OFF  3337280   // int flag (1 = inputs are bf16)
#define BUFX_BYTE 13349376  // bf16 [NN][1024]: y2
#define BUFY_BYTE 76263936  // bf16 [NN][1024]: y1

__device__ const int d_cum[27] = {
  0, 983040, 1064960, 1065088, 1065152, 1069248, 1069312, 1069376,
  1069440, 1073536, 1073600, 1073664, 1073728, 1135168, 1135232, 1145472,
  1151872, 1152032, 1152192, 1162432, 1168832, 1168992, 1169152, 1170432,
  1170448, 1170464, 1170465};

struct Ptrs { const void* p[26]; };

__device__ inline float b2f(u16 u) { return __uint_as_float(((u32)u) << 16); }
__device__ inline u16 f2b(float f) {
  u32 u = __float_as_uint(f);
  u32 r = (u + 0x7FFFu + ((u >> 16) & 1u)) >> 16;
  return (u16)r;
}
__device__ inline float sigf(float x) { return 1.0f / (1.0f + __expf(-x)); }

// ---------------- dtype detector ----------------
__global__ void k_detect(const u16* __restrict__ raw, int* __restrict__ flag) {
  __shared__ int bad;
  if (threadIdx.x == 0) bad = 0;
  __syncthreads();
  for (int i = threadIdx.x; i < 4096; i += 256) {
    float f = b2f(raw[i]);
    if (!(fabsf(f) < 1000.0f)) atomicOr(&bad, 1);
  }
  __syncthreads();
  if (threadIdx.x == 0) *flag = bad ? 0 : 1;
}

// ---------------- convert all float inputs to f32 staging ----------------
__global__ void k_convert(Ptrs ptrs, float* __restrict__ W) {
  int gid = blockIdx.x * 256 + threadIdx.x;
  if (gid >= CVT_TOTAL) return;
  int flag = *(const int*)(W + FLAG_OFF);
  int ti = 0;
  #pragma unroll
  for (int i = 1; i < 26; ++i) ti += (gid >= d_cum[i]);
  int j = gid - d_cum[ti];
  const void* src = ptrs.p[ti];
  W[gid] = flag ? b2f(((const u16*)src)[j]) : ((const float*)src)[j];
}

// ---------------- pre-swizzle MFMA B-frags (Wf, Wg1, Wg2) + WihT f/b ------
__global__ void k_preswz(float* __restrict__ W, u16* __restrict__ WfB) {
  int i = blockIdx.x * 256 + threadIdx.x;
  if (i < 61440) {
    int j = i & 7, lane = (i >> 3) & 63, kt = (i >> 9) & 3, ks = i >> 11;
    int kout = kt * 16 + (lane & 15);
    int m = ks * 32 + ((lane >> 4) << 3) + j;
    WfB[i] = f2b(W[P_WF + kout * 960 + m]);
  } else if (i < 69632) {
    int ii = i - 61440;
    int L = ii >> 12, r = ii & 4095;
    int j = r & 7, lane = (r >> 3) & 63, nt = (r >> 9) & 3, ks = (r >> 11) & 1;
    int h = ks * 32 + ((lane >> 4) << 3) + j;
    int k = nt * 16 + (lane & 15);
    WfB[i] = f2b(W[(L ? P_WG2 : P_WG1) + h * 64 + k]);
  } else if (i < 90112) {
    int e = i - 69632;
    int which = e / 10240, rem = e % 10240;
    int kk = rem / 160, jj = rem % 160;
    W[WIHT_OFF + e] = W[(which ? P_WIHB : P_WIHF) + jj * 64 + kk];
  }
}

// ---------------- fused GCN layer (1 block = 1 graph, 4 waves, MFMA) -------
// x recomputed in-LDS from data. LAYER==2 reads y1, builds x1=bn1(y1)+x in LDS.
// Epilogue bounces y through LDS (kg-swizzled) for coalesced uint4 stores.
template<int LAYER>
__global__ __launch_bounds__(256, 4)
void k_gcn(const float* __restrict__ W, const int* __restrict__ ei,
           const u16* __restrict__ bufIn, u16* __restrict__ bufOut,
           const u16* __restrict__ WgB,
           float* __restrict__ S1, float* __restrict__ S2,
           int bgoff, int scoff, int shoff) {
  __shared__ u16 s_x[15360];     // 30720 B, swizzled [v][t][h] bf16 (byte ^= (t&7)<<4)
  __shared__ float s_m[240];
  __shared__ float s_deg[16];
  __shared__ float s_d[480];     // data slice [v][f][t]
  __shared__ float s_w1[192];    // W1 [64][2] ++ b1 [64]

  int g = blockIdx.x, tid = threadIdx.x;

  // prefetch y1 tile (layer 2): all loads in flight before compute
  uint4 ld[8];
  if (LAYER == 2) {
    const uint4* py = (const uint4*)(bufIn + g * 15360);
    #pragma unroll
    for (int c = 0; c < 7; ++c) ld[c] = py[tid + c * 256];
    if (tid < 128) ld[7] = py[tid + 1792];
  }

  float ew = 0.f; int er = 0, ec = 0;
  if (tid < 40) {
    er = ei[g * 40 + tid] - g * 15;
    ec = ei[NE + g * 40 + tid] - g * 15;
    ew = W[F_EA + g * 40 + tid];
  }
  if (tid >= 40 && tid < 56) s_deg[tid - 40] = 1.0f;   // self-loop weight
  for (int i = tid; i < 240; i += 256) s_m[i] = 0.f;
  if (tid >= 64 && tid < 184) ((float4*)s_d)[tid - 64] = ((const float4*)(W + F_DATA + g * 480))[tid - 64];
  if (tid >= 192 && tid < 240) ((float4*)s_w1)[tid - 192] = ((const float4*)(W + P_W1))[tid - 192];
  __syncthreads();

  if (tid < 40) atomicAdd(&s_deg[ec], ew);
  // staging: x (L1) or x1=bn1(y1)+x (L2), bf16-swizzled into LDS
  #pragma unroll
  for (int c = 0; c < 8; ++c) {
    if (c < 7 || tid < 128) {
      int i = tid + c * 256;
      int v = i >> 7, rem = i & 127, t = rem >> 3, q = rem & 7;
      int h0 = q * 8;
      float d0 = s_d[v * 32 + t], d1 = s_d[v * 32 + 16 + t];
      u32 pk[4];
      if (LAYER == 1) {
        #pragma unroll
        for (int jp = 0; jp < 4; ++jp) {
          int h = h0 + jp * 2;
          float xa = fmaf(d0, s_w1[2 * h],     fmaf(d1, s_w1[2 * h + 1], s_w1[128 + h]));
          float xb = fmaf(d0, s_w1[2 * h + 2], fmaf(d1, s_w1[2 * h + 3], s_w1[129 + h]));
          pk[jp] = (u32)f2b(xa) | ((u32)f2b(xb) << 16);
        }
      } else {
        u32 uys[4] = {ld[c].x, ld[c].y, ld[c].z, ld[c].w};
        int th0 = t * 64 + h0;
        float4 A0 = *(const float4*)(W + scoff + th0), A1 = *(const float4*)(W + scoff + th0 + 4);
        float4 B0 = *(const float4*)(W + shoff + th0), B1 = *(const float4*)(W + shoff + th0 + 4);
        float scs[8] = {A0.x, A0.y, A0.z, A0.w, A1.x, A1.y, A1.z, A1.w};
        float shs[8] = {B0.x, B0.y, B0.z, B0.w, B1.x, B1.y, B1.z, B1.w};
        #pragma unroll
        for (int jp = 0; jp < 4; ++jp) {
          int j0 = jp * 2, h = h0 + j0;
          float xa = fmaf(d0, s_w1[2 * h],     fmaf(d1, s_w1[2 * h + 1], s_w1[128 + h]));
          float xb = fmaf(d0, s_w1[2 * h + 2], fmaf(d1, s_w1[2 * h + 3], s_w1[129 + h]));
          float a = fmaf(b2f((u16)(uys[jp] & 0xffff)), scs[j0],     shs[j0])     + xa;
          float b = fmaf(b2f((u16)(uys[jp] >> 16)),    scs[j0 + 1], shs[j0 + 1]) + xb;
          pk[jp] = (u32)f2b(a) | ((u32)f2b(b) << 16);
        }
      }
      u32 byte = ((u32)(i * 16)) ^ (((u32)(t & 7)) << 4);
      *(uint4*)((char*)s_x + byte) = make_uint4(pk[0], pk[1], pk[2], pk[3]);
    }
  }
  __syncthreads();
  if (tid < 15) s_deg[tid] = rsqrtf(s_deg[tid]);
  __syncthreads();
  if (tid < 40) atomicAdd(&s_m[ec * 16 + er], s_deg[er] * ew * s_deg[ec]);
  if (tid >= 64 && tid < 80) {
    float dv = s_deg[tid - 64];
    atomicAdd(&s_m[(tid - 64) * 17], dv * dv);
  }
  __syncthreads();

  // aggregation, in place: each thread owns 4 columns (2 u32 pairs)
  u32* sx32 = (u32*)s_x;
  {
    float x0[15], x1[15], x2[15], x3[15];
    int p0 = tid, p1 = tid + 256;
    int t0 = p0 >> 5, h0 = (2 * p0) & 63;
    int t1 = p1 >> 5, h1 = (2 * p1) & 63;
    u32 ba0 = ((u32)(t0 * 128 + h0 * 2)) ^ (((u32)(t0 & 7)) << 4);
    u32 ba1 = ((u32)(t1 * 128 + h1 * 2)) ^ (((u32)(t1 & 7)) << 4);
    #pragma unroll
    for (int v = 0; v < 15; ++v) {
      u32 ua = sx32[(ba0 + v * 2048) >> 2];
      u32 ub = sx32[(ba1 + v * 2048) >> 2];
      x0[v] = b2f((u16)(ua & 0xffff)); x1[v] = b2f((u16)(ua >> 16));
      x2[v] = b2f((u16)(ub & 0xffff)); x3[v] = b2f((u16)(ub >> 16));
    }
    #pragma unroll
    for (int vc = 0; vc < 15; ++vc) {
      float a0 = 0.f, a1 = 0.f, a2 = 0.f, a3 = 0.f;
      #pragma unroll
      for (int vr = 0; vr < 15; ++vr) {
        float m = s_m[vc * 16 + vr];
        a0 = fmaf(m, x0[vr], a0); a1 = fmaf(m, x1[vr], a1);
        a2 = fmaf(m, x2[vr], a2); a3 = fmaf(m, x3[vr], a3);
      }
      sx32[(ba0 + vc * 2048) >> 2] = (u32)f2b(a0) | ((u32)f2b(a1) << 16);
      sx32[(ba1 + vc * 2048) >> 2] = (u32)f2b(a2) | ((u32)f2b(a3) << 16);
    }
  }
  __syncthreads();

  // MFMA GEMM: y[v,t,k] = relu(agg[v,t,:] . Wg[:,k] + bg[k]); wave = n-tile
  int wid = tid >> 6, lane = tid & 63;
  int tA = lane & 15, kg = lane >> 4;
  const bf16x8* wb = (const bf16x8*)WgB;
  bf16x8 bf0 = wb[(0 * 4 + wid) * 64 + lane];
  bf16x8 bf1 = wb[(1 * 4 + wid) * 64 + lane];
  int kout = wid * 16 + tA;
  float bias = W[bgoff + kout];
  f32x4 acc[15];
  #pragma unroll
  for (int v = 0; v < 15; ++v) acc[v] = (f32x4){0.f, 0.f, 0.f, 0.f};
  u32 sw = ((u32)(tA & 7)) << 4;
  #pragma unroll
  for (int v = 0; v < 15; ++v) {
    u32 bb = (u32)(v * 2048 + tA * 128 + kg * 16);
    bf16x8 a0 = *(const bf16x8*)(s_x + ((bb ^ sw) >> 1));
    bf16x8 a1 = *(const bf16x8*)(s_x + (((bb + 64) ^ sw) >> 1));
    acc[v] = __builtin_amdgcn_mfma_f32_16x16x32_bf16(a0, bf0, acc[v], 0, 0, 0);
    acc[v] = __builtin_amdgcn_mfma_f32_16x16x32_bf16(a1, bf1, acc[v], 0, 0, 0);
  }

  // epilogue: bounce y through LDS (kg-swizzled; disjoint bank sets) then
  // coalesced uint4 global stores
  float s1r[4] = {0.f, 0.f, 0.f, 0.f}, s2r[4] = {0.f, 0.f, 0.f, 0.f};
  __syncthreads();                       // all A-frag reads complete
  #pragma unroll
  for (int v = 0; v < 15; ++v) {
    #pragma unroll
    for (int r = 0; r < 4; ++r) {
      float y = fmaxf(acc[v][r] + bias, 0.f);
      int t = kg * 4 + r;
      u32 byte = ((u32)(v * 2048 + t * 128 + kout * 2)) ^ (((u32)kg) << 5);
      *(u16*)((char*)s_x + byte) = f2b(y);
      s1r[r] += y; s2r[r] += y * y;
    }
  }
  __syncthreads();
  uint4* dst = (uint4*)(bufOut + g * 15360);
  const uint4* src = (const uint4*)s_x;
  #pragma unroll
  for (int c = 0; c < 8; ++c) {
    if (c < 7 || tid < 128) {
      int i = tid + c * 256;
      dst[i] = src[i ^ (((i >> 5) & 3) << 1)];   // undo kg-swizzle
    }
  }
  #pragma unroll
  for (int r = 0; r < 4; ++r) {
    int idx = (kg * 4 + r) * 64 + kout;
    atomicAdd(&S1[idx], s1r[r]);
    atomicAdd(&S2[idx], s2r[r]);
  }
}

// ---------------- finalize BN stats -> fused scale/shift ----------------
__global__ void k_finalize(float* __restrict__ W, int layer) {
  int i = blockIdx.x * 256 + threadIdx.x;
  if (i >= 1024) return;
  int base = STATS_OFF + (layer == 1 ? 0 : 2048);
  int scb  = STATS_OFF + (layer == 1 ? 4096 : 6144);
  float m   = W[base + i] * (1.0f / 30720.0f);
  float var = W[base + 1024 + i] * (1.0f / 30720.0f) - m * m;
  float istd = rsqrtf(var + 1e-5f);
  int h = i & 63;
  float gm = W[(layer == 1 ? P_G1 : P_G2) + h];
  float bt = W[(layer == 1 ? P_BE1 : P_BE2) + h];
  float sc = gm * istd;
  W[scb + i] = sc;
  W[scb + 1024 + i] = bt - m * sc;
}

// ---------------- fc1 via MFMA: in = bn2(y2)+bn1(y1)+x(recomputed) ---------
__global__ __launch_bounds__(256, 4)
void k_fc1(const float* __restrict__ W, const u16* __restrict__ bufY2,
           const u16* __restrict__ bufY1, const u16* __restrict__ WfB,
           float* __restrict__ Xs) {
  __shared__ u16 s_x[15360];
  __shared__ float s_d[480];
  __shared__ float s_w1[192];
  int g = blockIdx.x, tid = threadIdx.x;
  if (tid < 120) ((float4*)s_d)[tid] = ((const float4*)(W + F_DATA + g * 480))[tid];
  if (tid >= 128 && tid < 176) ((float4*)s_w1)[tid - 128] = ((const float4*)(W + P_W1))[tid - 128];
  __syncthreads();
  const uint4* py2 = (const uint4*)(bufY2 + g * 15360);
  const uint4* py1 = (const uint4*)(bufY1 + g * 15360);
  #pragma unroll
  for (int c = 0; c < 8; ++c) {
    if (c < 7 || tid < 128) {
      int i = tid + c * 256;
      int v = i >> 7, rem = i & 127, t = rem >> 3, q = rem & 7;
      int h0 = q * 8, th0 = t * 64 + h0;
      uint4 u2 = py2[i], u1 = py1[i];
      u32 u2s[4] = {u2.x, u2.y, u2.z, u2.w}, u1s[4] = {u1.x, u1.y, u1.z, u1.w};
      float d0 = s_d[v * 32 + t], d1 = s_d[v * 32 + 16 + t];
      float4 A0 = *(const float4*)(W + STATS_OFF + 6144 + th0), A1 = *(const float4*)(W + STATS_OFF + 6148 + th0);
      float4 B0 = *(const float4*)(W + STATS_OFF + 7168 + th0), B1 = *(const float4*)(W + STATS_OFF + 7172 + th0);
      float4 C0 = *(const float4*)(W + STATS_OFF + 4096 + th0), C1 = *(const float4*)(W + STATS_OFF + 4100 + th0);
      float4 D0 = *(const float4*)(W + STATS_OFF + 5120 + th0), D1 = *(const float4*)(W + STATS_OFF + 5124 + th0);
      float sc2[8] = {A0.x, A0.y, A0.z, A0.w, A1.x, A1.y, A1.z, A1.w};
      float sh2[8] = {B0.x, B0.y, B0.z, B0.w, B1.x, B1.y, B1.z, B1.w};
      float sc1[8] = {C0.x, C0.y, C0.z, C0.w, C1.x, C1.y, C1.z, C1.w};
      float sh1[8] = {D0.x, D0.y, D0.z, D0.w, D1.x, D1.y, D1.z, D1.w};
      u32 pk[4];
      #pragma unroll
      for (int jp = 0; jp < 4; ++jp) {
        int j0 = jp * 2, h = h0 + j0;
        float xa = fmaf(d0, s_w1[2 * h],     fmaf(d1, s_w1[2 * h + 1], s_w1[128 + h]));
        float xb = fmaf(d0, s_w1[2 * h + 2], fmaf(d1, s_w1[2 * h + 3], s_w1[129 + h]));
        float x1a = fmaf(b2f((u16)(u1s[jp] & 0xffff)), sc1[j0],     sh1[j0])     + xa;
        float x1b = fmaf(b2f((u16)(u1s[jp] >> 16)),    sc1[j0 + 1], sh1[j0 + 1]) + xb;
        float a = fmaf(b2f((u16)(u2s[jp] & 0xffff)), sc2[j0],     sh2[j0])     + x1a;
        float b = fmaf(b2f((u16)(u2s[jp] >> 16)),    sc2[j0 + 1], sh2[j0 + 1]) + x1b;
        pk[jp] = (u32)f2b(a) | ((u32)f2b(b) << 16);
      }
      u32 byte = ((u32)(i * 16)) ^ (((u32)(t & 7)) << 4);
      *(uint4*)((char*)s_x + byte) = make_uint4(pk[0], pk[1], pk[2], pk[3]);
    }
  }
  __syncthreads();

  int wid = tid >> 6, lane = tid & 63;
  int tA = lane & 15, kg = lane >> 4;
  f32x4 acc = {0.f, 0.f, 0.f, 0.f};
  const bf16x8* wf = (const bf16x8*)WfB;
  #pragma unroll 2
  for (int ks = 0; ks < 30; ++ks) {
    int v = ks >> 1, half = ks & 1;
    u32 byte = (u32)(v * 2048 + tA * 128 + (half * 32 + kg * 8) * 2) ^ (((u32)(tA & 7)) << 4);
    bf16x8 afrag = *(const bf16x8*)(s_x + (byte >> 1));
    bf16x8 bfrag = wf[(ks * 4 + wid) * 64 + lane];
    acc = __builtin_amdgcn_mfma_f32_16x16x32_bf16(afrag, bfrag, acc, 0, 0, 0);
  }
  int kout = wid * 16 + (lane & 15);
  float bias = W[P_BF + kout];
  #pragma unroll
  for (int r = 0; r < 4; ++r) {
    int t = (lane >> 4) * 4 + r;
    Xs[t * 131072 + g * 64 + kout] = fmaxf(acc[r] + bias, 0.0f);
  }
}

// ---------------- LSTM: fused gate-GEMM (registers) + recurrence + head ----
// 512 thr = 8 waves; wave r owns batch row r0+r. Gate-x for all 16 steps is
// computed into registers (same FP order as the old gatex kernel).
__global__ __launch_bounds__(512)
void k_lstm2(const float* __restrict__ W, const float* __restrict__ Xs,
             void* __restrict__ dout, const int* __restrict__ flagp) {
  extern __shared__ float smem[];
  float* s_whh = smem;            // 40*162 = 6480
  float* s_xs  = smem + 6480;     // [t][b][k] 16*8*64 = 8192
  float* s_h   = smem + 14672;    // 320
  float* s_c   = smem + 14992;    // 320
  float* s_hb  = smem + 15312;    // 320
  float* s_g   = smem + 15632;    // 1280
  float* s_cls = smem + 16912;    // 128  (total 17040 f32 = 68160 B)
  int tid = threadIdx.x, r0 = blockIdx.x * 8;

  for (int i = tid; i < 6400; i += 512) {
    int jj = i / 40, kk = i % 40;
    s_whh[kk * 162 + jj] = W[P_WHHF + i];
  }
  #pragma unroll
  for (int c = 0; c < 4; ++c) {
    int i4 = tid + c * 512;
    int i = i4 * 4;
    int t = i >> 9, b = (i >> 6) & 7, k = i & 63;
    ((float4*)s_xs)[i4] = *(const float4*)(Xs + t * 131072 + (r0 + b) * 64 + k);
  }
  if (tid < 320) { s_h[tid] = 0.f; s_c[tid] = 0.f; }
  __syncthreads();

  int r = tid >> 6, l = tid & 63;
  int l2 = (l < 32) ? l + 128 : l;      // duplicate cols for l>=32 (unused writes masked)
  float G0[16], G1[16], G2[16];
  {
    float b0 = W[P_BIHF + l]      + W[P_BHHF + l];
    float b1 = W[P_BIHF + l + 64] + W[P_BHHF + l + 64];
    float b2 = W[P_BIHF + l2]     + W[P_BHHF + l2];
    #pragma unroll
    for (int t = 0; t < 16; ++t) { G0[t] = b0; G1[t] = b1; G2[t] = b2; }
    const float* wih = W + WIHT_OFF;
    const float* xr = s_xs + r * 64;
    for (int kk = 0; kk < 64; ++kk) {
      float w0 = wih[kk * 160 + l];
      float w1 = wih[kk * 160 + l + 64];
      float w2 = wih[kk * 160 + l2];
      #pragma unroll
      for (int t = 0; t < 16; ++t) {
        float xv = xr[t * 512 + kk];
        G0[t] = fmaf(xv, w0, G0[t]);
        G1[t] = fmaf(xv, w1, G1[t]);
        G2[t] = fmaf(xv, w2, G2[t]);
      }
    }
  }

  #pragma unroll
  for (int t = 0; t < 16; ++t) {
    float acc0 = G0[t], acc1 = G1[t], acc2 = G2[t];
    const float* hr = s_h + r * 40;
    #pragma unroll 8
    for (int kk = 0; kk < 40; ++kk) {
      float hv = hr[kk];
      acc0 = fmaf(hv, s_whh[kk * 162 + l], acc0);
      acc1 = fmaf(hv, s_whh[kk * 162 + l + 64], acc1);
      acc2 = fmaf(hv, s_whh[kk * 162 + l2], acc2);
    }
    s_g[r * 160 + l] = acc0;
    s_g[r * 160 + l + 64] = acc1;
    if (l < 32) s_g[r * 160 + l2] = acc2;
    __syncthreads();
    if (tid < 320) {
      int row = tid / 40, jj = tid % 40;
      const float* gr = s_g + row * 160;
      float ig = gr[jj], fg = gr[jj + 40], gg = gr[jj + 80], og = gr[jj + 120];
      float c = sigf(fg) * s_c[tid] + sigf(ig) * tanhf(gg);
      s_c[tid] = c;
      s_h[tid] = sigf(og) * tanhf(c);
    }
    __syncthreads();
  }

  // bwd LSTM first step from zero state on Xs[15]: compute inline
  if (tid < 320) {
    int row = tid / 40, jj = tid % 40;
    const float* wb = W + WIHT_OFF + 10240;
    float ai = W[P_BIHB + jj]       + W[P_BHHB + jj];
    float ag = W[P_BIHB + jj + 80]  + W[P_BHHB + jj + 80];
    float ao = W[P_BIHB + jj + 120] + W[P_BHHB + jj + 120];
    const float* xr = s_xs + 15 * 512 + row * 64;
    for (int kk = 0; kk < 64; ++kk) {
      float xv = xr[kk];
      ai = fmaf(xv, wb[kk * 160 + jj], ai);
      ag = fmaf(xv, wb[kk * 160 + jj + 80], ag);
      ao = fmaf(xv, wb[kk * 160 + jj + 120], ao);
    }
    float c = sigf(ai) * tanhf(ag);
    s_hb[tid] = sigf(ao) * tanhf(c);
  }
  __syncthreads();

  if (tid < 128) {
    int rr = tid >> 4, jj = tid & 15;
    float a = W[P_BC1 + jj];
    for (int p = 0; p < 40; ++p) a = fmaf(W[P_WC1 + jj * 80 + p],      s_h[rr * 40 + p],  a);
    for (int p = 0; p < 40; ++p) a = fmaf(W[P_WC1 + jj * 80 + 40 + p], s_hb[rr * 40 + p], a);
    s_cls[rr * 16 + jj] = fmaxf(a, 0.0f);
  }
  __syncthreads();
  if (tid < 8) {
    float o = W[P_BC2];
    #pragma unroll
    for (int jj = 0; jj < 16; ++jj) o = fmaf(W[P_WC2 + jj], s_cls[tid * 16 + jj], o);
    if (*flagp) ((u16*)dout)[r0 + tid] = f2b(o);
    else        ((float*)dout)[r0 + tid] = o;
  }
}

// ---------------- launch ----------------
extern "C" void kernel_launch(void* const* d_in, const int* in_sizes, int n_in,
                              void* d_out, int out_size, void* d_ws, size_t ws_size,
                              hipStream_t stream) {
  float* W = (float*)d_ws;
  u16* bufX = (u16*)((char*)d_ws + BUFX_BYTE);   // y2
  u16* bufY = (u16*)((char*)d_ws + BUFY_BYTE);   // y1
  u16* WfB  = (u16*)(W + WFB_OFF);
  const int* ei = (const int*)d_in[26];

  (void)hipFuncSetAttribute(reinterpret_cast<const void*>(&k_lstm2),
                            hipFuncAttributeMaxDynamicSharedMemorySize, 68160);

  hipMemsetAsync(W + STATS_OFF, 0, 4096 * sizeof(float), stream);
  k_detect<<<1, 256, 0, stream>>>((const u16*)d_in[0], (int*)(W + FLAG_OFF));
  Ptrs ptrs;
  for (int i = 0; i < 26; ++i) ptrs.p[i] = d_in[i];
  k_convert<<<(CVT_TOTAL + 255) / 256, 256, 0, stream>>>(ptrs, W);
  k_preswz<<<352, 256, 0, stream>>>(W, WfB);
  k_gcn<1><<<NB, 256, 0, stream>>>(W, ei, nullptr, bufY, WfB + 61440,
      W + STATS_OFF, W + STATS_OFF + 1024, P_BG1, 0, 0);
  k_finalize<<<4, 256, 0, stream>>>(W, 1);
  k_gcn<2><<<NB, 256, 0, stream>>>(W, ei, bufY, bufX, WfB + 65536,
      W + STATS_OFF + 2048, W + STATS_OFF + 3072, P_BG2,
      STATS_OFF + 4096, STATS_OFF + 5120);
  k_finalize<<<4, 256, 0, stream>>>(W, 2);
  k_fc1<<<NB, 256, 0, stream>>>(W, bufX, bufY, WfB, W + XS_OFF);
  k_lstm2<<<256, 512, 68160, stream>>>(W, W + XS_OFF, d_out, (const int*)(W + FLAG_OFF));
}